// Round 4
// baseline (729.416 us; speedup 1.0000x reference)
//
#include <hip/hip_runtime.h>

#define BATCH 4
#define SEQ   2048
#define EMB   512
#define HEADS 8
#define HD    64

typedef _Float16 half4_t __attribute__((ext_vector_type(4)));
typedef _Float16 half8_t __attribute__((ext_vector_type(8)));
typedef float    f32x4   __attribute__((ext_vector_type(4)));

// ---------------------------------------------------------------- mod factor
__global__ void mod_kernel(const float* __restrict__ emo, float* __restrict__ modv){
    int lane = threadIdx.x;                 // 64 threads, 1 wave
    for (int b = 0; b < BATCH; ++b){
        float v = emo[b*64 + lane];
        #pragma unroll
        for (int off = 32; off >= 1; off >>= 1) v += __shfl_xor(v, off, 64);
        if (lane == 0){
            float mean = v * (1.0f/64.0f);
            float sig  = 1.0f/(1.0f + __expf(-mean));
            modv[b] = 0.5f + 0.5f*sig;
        }
    }
}

__device__ inline half8_t cvt8(const float* p){
    float4 v0 = *(const float4*)p;
    float4 v1 = *(const float4*)(p + 4);
    half8_t r;
    r[0]=(_Float16)v0.x; r[1]=(_Float16)v0.y; r[2]=(_Float16)v0.z; r[3]=(_Float16)v0.w;
    r[4]=(_Float16)v1.x; r[5]=(_Float16)v1.y; r[6]=(_Float16)v1.z; r[7]=(_Float16)v1.w;
    return r;
}

// ------------------------------------------------- QKV projection (f32 -> f16)
// 64x64 block tile, 4 waves of 32x32, grid (128,8) = 1024 blocks (4/CU).
// transposed==0 : out[((b*8+h)*2048+s)*64 + d]   (Q,K layout)
// transposed==1 : out[((b*8+h)*64 + d)*2048 + s] (V^T layout)
__global__ __launch_bounds__(256) void proj_kernel(
    const float* __restrict__ X, const float* __restrict__ W,
    const float* __restrict__ bias, _Float16* __restrict__ out, int transposed)
{
    const int tid  = threadIdx.x;
    const int wid  = tid >> 6;
    const int lane = tid & 63;
    const int l16  = lane & 15;
    const int g    = lane >> 4;
    const int m0 = blockIdx.x*64 + (wid >> 1)*32;
    const int n0 = blockIdx.y*64 + (wid & 1)*32;

    f32x4 acc[2][2] = {};
    for (int kk = 0; kk < 16; ++kk){
        const int k0 = kk*32 + 8*g;
        half8_t a[2], bb[2];
        #pragma unroll
        for (int i = 0; i < 2; ++i){
            a[i]  = cvt8(X + (size_t)(m0 + i*16 + l16)*EMB + k0);
            bb[i] = cvt8(W + (size_t)(n0 + i*16 + l16)*EMB + k0);
        }
        #pragma unroll
        for (int i = 0; i < 2; ++i)
            #pragma unroll
            for (int j = 0; j < 2; ++j)
                acc[i][j] = __builtin_amdgcn_mfma_f32_16x16x32_f16(a[i], bb[j], acc[i][j], 0, 0, 0);
    }
    #pragma unroll
    for (int j = 0; j < 2; ++j){
        const int n  = n0 + j*16 + l16;
        const float bn = bias[n];
        const int h = n >> 6, d = n & 63;
        #pragma unroll
        for (int i = 0; i < 2; ++i){
            #pragma unroll
            for (int r = 0; r < 4; ++r){
                const int m  = m0 + i*16 + 4*g + r;
                const int bb2 = m >> 11, s = m & 2047;
                const float v = acc[i][j][r] + bn;
                size_t idx = transposed ? ((size_t)((bb2*8 + h)*64 + d)*SEQ + s)
                                        : ((size_t)((bb2*8 + h)*SEQ + s)*64 + d);
                out[idx] = (_Float16)v;
            }
        }
    }
}

// ---------------------------------------------------- pass 1: PV + denominators
// One block per (b,h,64 q-rows): 4 waves x 16 q-rows. One-pass unnormalized
// accumulation (logits bounded, no max shift): acc = sum e*V, L = sum e;
// scale by 1/L at the end. No LDS, no barriers. Writes attended (f16) + L.
__global__ __launch_bounds__(256) void pv_kernel(
    const _Float16* __restrict__ Qp, const _Float16* __restrict__ Kp,
    const _Float16* __restrict__ Vt, const float* __restrict__ emo_bias,
    const float* __restrict__ modv, _Float16* __restrict__ attended,
    float* __restrict__ Ldenom)
{
    const int tid  = threadIdx.x;
    const int w    = tid >> 6;
    const int lane = tid & 63;
    const int l16  = lane & 15;
    const int g    = lane >> 4;
    // XCD-aware swizzle, BIJECTIVE for 1024 blocks: 8 XCDs x 128 contiguous
    // work items each (R2/R3 bug: used *256, leaving half the tiles unwritten
    // and indexing bh up to 59 -> OOB).
    const int n    = blockIdx.x;
    const int work = (n & 7)*128 + (n >> 3);
    const int qt   = work & 31;           // SEQ/64 = 32 q-tiles
    const int bh   = work >> 5;           // b*8 + h, in [0,32)
    const int b    = bh >> 3, h = bh & 7;
    const int q0   = qt*64 + w*16;

    const float mod = modv[b];
    const float sm  = 0.125f * mod;
    const float bm  = emo_bias[h] * mod;

    const size_t ho = (size_t)bh * SEQ * HD;
    const _Float16* Qh = Qp + ho;
    const _Float16* Kh = Kp + ho;
    const _Float16* Vh = Vt + ho;         // [HD][SEQ]

    half8_t qf[2];
    #pragma unroll
    for (int c = 0; c < 2; ++c)
        qf[c] = *(const half8_t*)(Qh + (size_t)(q0 + l16)*HD + c*32 + 8*g);

    f32x4 acc[4] = {};
    float lsum = 0.f;
    for (int kt = 0; kt < SEQ/16; ++kt){
        const int k0 = kt * 16;
        half8_t kf0 = *(const half8_t*)(Kh + (size_t)(k0 + l16)*HD + 8*g);
        half8_t kf1 = *(const half8_t*)(Kh + (size_t)(k0 + l16)*HD + 32 + 8*g);
        f32x4 s = {};
        s = __builtin_amdgcn_mfma_f32_16x16x32_f16(kf0, qf[0], s, 0, 0, 0);
        s = __builtin_amdgcn_mfma_f32_16x16x32_f16(kf1, qf[1], s, 0, 0, 0);
        // lane holds (q = q0 + l16, k = k0 + 4g + r)
        float e0 = __expf(s[0]*sm + bm);
        float e1 = __expf(s[1]*sm + bm);
        float e2 = __expf(s[2]*sm + bm);
        float e3 = __expf(s[3]*sm + bm);
        lsum += (e0 + e1) + (e2 + e3);
        half4_t pf;
        pf[0]=(_Float16)e0; pf[1]=(_Float16)e1; pf[2]=(_Float16)e2; pf[3]=(_Float16)e3;
        #pragma unroll
        for (int c = 0; c < 4; ++c){
            half4_t vf = *(const half4_t*)(Vh + (size_t)(16*c + l16)*SEQ + k0 + 4*g);
            acc[c] = __builtin_amdgcn_mfma_f32_16x16x16f16(pf, vf, acc[c], 0, 0, 0);
        }
    }
    // row denominators: lane's lsum covers q=l16; reduce over g groups
    lsum += __shfl_xor(lsum, 16, 64);
    lsum += __shfl_xor(lsum, 32, 64);
    if (g == 0) Ldenom[(size_t)bh*SEQ + q0 + l16] = lsum;
    const float inv = 1.0f / lsum;        // for q = l16
    float invr[4];
    #pragma unroll
    for (int r = 0; r < 4; ++r)
        invr[r] = __shfl(inv, 4*g + r, 64);   // redistribute to q = 4g+r rows
    // store: acc row = q0+4g+r, col = h*64 + 16c + l16
    #pragma unroll
    for (int c = 0; c < 4; ++c)
        #pragma unroll
        for (int r = 0; r < 4; ++r)
            attended[(size_t)(b*SEQ + q0 + 4*g + r)*EMB + h*64 + 16*c + l16]
                = (_Float16)(acc[c][r] * invr[r]);
}

// ------------------------------------------- pass 2: softmax mean over heads
// One block per (b, 16 q-rows, 256 k-cols): 4 waves x 64 k. Heads looped in
// registers; lane holds all 8 heads' p for its (q,k) -> in-register mean.
// No LDS, no barriers.
__global__ __launch_bounds__(256) void mean_kernel(
    const _Float16* __restrict__ Qp, const _Float16* __restrict__ Kp,
    const float* __restrict__ emo_bias, const float* __restrict__ modv,
    const float* __restrict__ Ldenom, float* __restrict__ mean_out)
{
    const int tid  = threadIdx.x;
    const int w    = tid >> 6;
    const int lane = tid & 63;
    const int l16  = lane & 15;
    const int g    = lane >> 4;
    // 4096 blocks, bijective XCD swizzle; work = b*1024 + ky*128 + qt
    const int n    = blockIdx.x;
    const int work = (n & 7)*512 + (n >> 3);
    const int b    = work >> 10;
    const int ky   = (work >> 7) & 7;
    const int qt   = work & 127;
    const int q0   = qt * 16;
    const int k0w  = ky*256 + w*64;

    const float mod = modv[b];
    const float sm  = 0.125f * mod;

    f32x4 msum[4] = {};                    // [j]: k = k0w + j*16 + l16, q = q0 + 4g + r
    for (int h = 0; h < HEADS; ++h){
        const size_t ho = (size_t)(b*HEADS + h) * SEQ;
        const float bm = emo_bias[h] * mod;
        half8_t qf0 = *(const half8_t*)(Qp + (ho + q0 + l16)*HD + 8*g);
        half8_t qf1 = *(const half8_t*)(Qp + (ho + q0 + l16)*HD + 32 + 8*g);
        float invL[4];
        #pragma unroll
        for (int r = 0; r < 4; ++r)
            invL[r] = 1.0f / Ldenom[ho + q0 + 4*g + r];
        #pragma unroll
        for (int j = 0; j < 4; ++j){
            const int k0 = k0w + j*16;
            half8_t kf0 = *(const half8_t*)(Kp + (ho + k0 + l16)*HD + 8*g);
            half8_t kf1 = *(const half8_t*)(Kp + (ho + k0 + l16)*HD + 32 + 8*g);
            f32x4 s = {};
            s = __builtin_amdgcn_mfma_f32_16x16x32_f16(qf0, kf0, s, 0, 0, 0);
            s = __builtin_amdgcn_mfma_f32_16x16x32_f16(qf1, kf1, s, 0, 0, 0);
            #pragma unroll
            for (int r = 0; r < 4; ++r)
                msum[j][r] += __expf(s[r]*sm + bm) * invL[r];
        }
    }
    #pragma unroll
    for (int j = 0; j < 4; ++j)
        #pragma unroll
        for (int r = 0; r < 4; ++r)
            mean_out[(size_t)(b*SEQ + q0 + 4*g + r)*SEQ + k0w + j*16 + l16]
                = msum[j][r] * (1.0f/HEADS);
}

// ------------------------------------------------------ output projection f32
__global__ __launch_bounds__(256) void outproj_kernel(
    const _Float16* __restrict__ A, const float* __restrict__ W,
    const float* __restrict__ bias, float* __restrict__ out)
{
    const int tid  = threadIdx.x;
    const int wid  = tid >> 6;
    const int lane = tid & 63;
    const int l16  = lane & 15;
    const int g    = lane >> 4;
    const int m0 = blockIdx.x*64 + (wid >> 1)*32;
    const int n0 = blockIdx.y*64 + (wid & 1)*32;

    f32x4 acc[2][2] = {};
    for (int kk = 0; kk < 16; ++kk){
        const int k0 = kk*32 + 8*g;
        half8_t a[2], bb[2];
        #pragma unroll
        for (int i = 0; i < 2; ++i){
            a[i]  = *(const half8_t*)(A + (size_t)(m0 + i*16 + l16)*EMB + k0);
            bb[i] = cvt8(W + (size_t)(n0 + i*16 + l16)*EMB + k0);
        }
        #pragma unroll
        for (int i = 0; i < 2; ++i)
            #pragma unroll
            for (int j = 0; j < 2; ++j)
                acc[i][j] = __builtin_amdgcn_mfma_f32_16x16x32_f16(a[i], bb[j], acc[i][j], 0, 0, 0);
    }
    #pragma unroll
    for (int j = 0; j < 2; ++j){
        const int n = n0 + j*16 + l16;
        const float bn = bias[n];
        #pragma unroll
        for (int i = 0; i < 2; ++i)
            #pragma unroll
            for (int r = 0; r < 4; ++r){
                const int m = m0 + i*16 + 4*g + r;
                out[(size_t)m*EMB + n] = acc[i][j][r] + bn;
            }
    }
}

// ---------------------------------------------------------------------- host
extern "C" void kernel_launch(void* const* d_in, const int* in_sizes, int n_in,
                              void* d_out, int out_size, void* d_ws, size_t ws_size,
                              hipStream_t stream)
{
    const float* query = (const float*)d_in[0];
    const float* key_  = (const float*)d_in[1];
    const float* value = (const float*)d_in[2];
    const float* emo   = (const float*)d_in[3];
    const float* Wq = (const float*)d_in[4];
    const float* bq = (const float*)d_in[5];
    const float* Wk = (const float*)d_in[6];
    const float* bk = (const float*)d_in[7];
    const float* Wv = (const float*)d_in[8];
    const float* bv = (const float*)d_in[9];
    const float* Wo = (const float*)d_in[10];
    const float* bo = (const float*)d_in[11];
    const float* emo_bias = (const float*)d_in[12];

    const size_t NTOK = (size_t)BATCH * SEQ * EMB;   // 4,194,304
    _Float16* ws       = (_Float16*)d_ws;
    _Float16* Qp       = ws;                          // ws usage: exactly 32 MiB
    _Float16* Kp       = ws + NTOK;
    _Float16* Vt       = ws + 2*NTOK;
    _Float16* attended = ws + 3*NTOK;

    float* out0     = (float*)d_out;
    float* mean_out = out0 + NTOK;
    // Small scratch lives in the output-0 region (16 MB): written/read by the
    // early kernels, fully overwritten by outproj_kernel at the end.
    float* Ldenom   = out0;                           // BATCH*HEADS*SEQ = 65536 f32
    float* modv     = out0 + (size_t)BATCH*HEADS*SEQ; // 4 f32

    mod_kernel<<<1, 64, 0, stream>>>(emo, modv);
    dim3 pg(128, 8);
    proj_kernel<<<pg, 256, 0, stream>>>(query, Wq, bq, Qp, 0);
    proj_kernel<<<pg, 256, 0, stream>>>(key_,  Wk, bk, Kp, 0);
    proj_kernel<<<pg, 256, 0, stream>>>(value, Wv, bv, Vt, 1);
    pv_kernel<<<BATCH*HEADS*(SEQ/64), 256, 0, stream>>>(Qp, Kp, Vt, emo_bias, modv, attended, Ldenom);
    mean_kernel<<<BATCH*(SEQ/16)*(SEQ/256), 256, 0, stream>>>(Qp, Kp, emo_bias, modv, Ldenom, mean_out);
    outproj_kernel<<<pg, 256, 0, stream>>>(attended, Wo, bo, out0);
}

// Round 5
// 713.876 us; speedup vs baseline: 1.0218x; 1.0218x over previous
//
#include <hip/hip_runtime.h>

#define BATCH 4
#define SEQ   2048
#define EMB   512
#define HEADS 8
#define HD    64

typedef _Float16 half4_t __attribute__((ext_vector_type(4)));
typedef _Float16 half8_t __attribute__((ext_vector_type(8)));
typedef float    f32x4   __attribute__((ext_vector_type(4)));

// ---------------------------------------------------------------- mod factor
__global__ void mod_kernel(const float* __restrict__ emo, float* __restrict__ modv){
    int lane = threadIdx.x;                 // 64 threads, 1 wave
    for (int b = 0; b < BATCH; ++b){
        float v = emo[b*64 + lane];
        #pragma unroll
        for (int off = 32; off >= 1; off >>= 1) v += __shfl_xor(v, off, 64);
        if (lane == 0){
            float mean = v * (1.0f/64.0f);
            float sig  = 1.0f/(1.0f + __expf(-mean));
            modv[b] = 0.5f + 0.5f*sig;
        }
    }
}

__device__ inline half8_t cvt8(const float* p){
    float4 v0 = *(const float4*)p;
    float4 v1 = *(const float4*)(p + 4);
    half8_t r;
    r[0]=(_Float16)v0.x; r[1]=(_Float16)v0.y; r[2]=(_Float16)v0.z; r[3]=(_Float16)v0.w;
    r[4]=(_Float16)v1.x; r[5]=(_Float16)v1.y; r[6]=(_Float16)v1.z; r[7]=(_Float16)v1.w;
    return r;
}

// --------------------------------------- QKV projections, one launch (z=0,1,2)
// 64x64 block tile, 4 waves of 32x32, k-unrolled x2 (16 loads in flight).
// z==2 (V) writes transposed [bh][d][s]; z==0,1 write [bh][s][d].
__global__ __launch_bounds__(256) void qkv_kernel(
    const float* __restrict__ X0, const float* __restrict__ X1, const float* __restrict__ X2,
    const float* __restrict__ W0, const float* __restrict__ W1, const float* __restrict__ W2,
    const float* __restrict__ b0, const float* __restrict__ b1, const float* __restrict__ b2,
    _Float16* __restrict__ o0, _Float16* __restrict__ o1, _Float16* __restrict__ o2)
{
    const int z = blockIdx.z;
    const float* X    = (z==0) ? X0 : (z==1) ? X1 : X2;
    const float* W    = (z==0) ? W0 : (z==1) ? W1 : W2;
    const float* bias = (z==0) ? b0 : (z==1) ? b1 : b2;
    _Float16*  out    = (z==0) ? o0 : (z==1) ? o1 : o2;
    const int transposed = (z==2);

    const int tid  = threadIdx.x;
    const int wid  = tid >> 6;
    const int lane = tid & 63;
    const int l16  = lane & 15;
    const int g    = lane >> 4;
    const int m0 = blockIdx.x*64 + (wid >> 1)*32;
    const int n0 = blockIdx.y*64 + (wid & 1)*32;

    f32x4 acc[2][2] = {};
    for (int kk = 0; kk < 8; ++kk){         // 2 x 32-k chunks per iteration
        half8_t a[2][2], bb[2][2];
        #pragma unroll
        for (int u = 0; u < 2; ++u){
            const int k0 = kk*64 + u*32 + 8*g;
            #pragma unroll
            for (int i = 0; i < 2; ++i){
                a[u][i]  = cvt8(X + (size_t)(m0 + i*16 + l16)*EMB + k0);
                bb[u][i] = cvt8(W + (size_t)(n0 + i*16 + l16)*EMB + k0);
            }
        }
        #pragma unroll
        for (int u = 0; u < 2; ++u)
            #pragma unroll
            for (int i = 0; i < 2; ++i)
                #pragma unroll
                for (int j = 0; j < 2; ++j)
                    acc[i][j] = __builtin_amdgcn_mfma_f32_16x16x32_f16(a[u][i], bb[u][j], acc[i][j], 0, 0, 0);
    }
    #pragma unroll
    for (int j = 0; j < 2; ++j){
        const int n  = n0 + j*16 + l16;
        const float bn = bias[n];
        const int h = n >> 6, d = n & 63;
        #pragma unroll
        for (int i = 0; i < 2; ++i){
            #pragma unroll
            for (int r = 0; r < 4; ++r){
                const int m  = m0 + i*16 + 4*g + r;
                const int bb2 = m >> 11, s = m & 2047;
                const float v = acc[i][j][r] + bn;
                size_t idx = transposed ? ((size_t)((bb2*8 + h)*64 + d)*SEQ + s)
                                        : ((size_t)((bb2*8 + h)*SEQ + s)*64 + d);
                out[idx] = (_Float16)v;
            }
        }
    }
}

// ---------------------------------------------------- pass 1: PV + denominators
// One block per (b,h,64 q-rows): 4 waves x 16 q-rows. K-loop unrolled x4
// (64 keys/iter): 24 loads issued up front, 4 independent QK chains, 16 exps,
// 16 PV MFMAs over 4 independent accumulators. No LDS, no barriers.
__global__ __launch_bounds__(256) void pv_kernel(
    const _Float16* __restrict__ Qp, const _Float16* __restrict__ Kp,
    const _Float16* __restrict__ Vt, const float* __restrict__ emo_bias,
    const float* __restrict__ modv, _Float16* __restrict__ attended,
    float* __restrict__ Ldenom)
{
    const int tid  = threadIdx.x;
    const int w    = tid >> 6;
    const int lane = tid & 63;
    const int l16  = lane & 15;
    const int g    = lane >> 4;
    // bijective XCD swizzle for 1024 blocks: 8 XCDs x 128
    const int n    = blockIdx.x;
    const int work = (n & 7)*128 + (n >> 3);
    const int qt   = work & 31;           // SEQ/64 = 32 q-tiles
    const int bh   = work >> 5;           // in [0,32)
    const int b    = bh >> 3, h = bh & 7;
    const int q0   = qt*64 + w*16;

    const float mod = modv[b];
    const float sm  = 0.125f * mod;
    const float bm  = emo_bias[h] * mod;

    const size_t ho = (size_t)bh * SEQ * HD;
    const _Float16* Qh = Qp + ho;
    const _Float16* Kh = Kp + ho;
    const _Float16* Vh = Vt + ho;         // [HD][SEQ]

    half8_t qf[2];
    #pragma unroll
    for (int c = 0; c < 2; ++c)
        qf[c] = *(const half8_t*)(Qh + (size_t)(q0 + l16)*HD + c*32 + 8*g);

    f32x4 acc[4] = {};
    float lsum = 0.f;
    for (int kt = 0; kt < SEQ/64; ++kt){
        const int k0 = kt * 64;
        // ---- issue all loads for 4 K-tiles (8 K + 16 V)
        half8_t kf[4][2];
        half4_t vf[4][4];
        #pragma unroll
        for (int t = 0; t < 4; ++t){
            kf[t][0] = *(const half8_t*)(Kh + (size_t)(k0 + 16*t + l16)*HD + 8*g);
            kf[t][1] = *(const half8_t*)(Kh + (size_t)(k0 + 16*t + l16)*HD + 32 + 8*g);
            #pragma unroll
            for (int c = 0; c < 4; ++c)
                vf[t][c] = *(const half4_t*)(Vh + (size_t)(16*c + l16)*SEQ + k0 + 16*t + 4*g);
        }
        // ---- 4 independent QK chains
        f32x4 s[4];
        #pragma unroll
        for (int t = 0; t < 4; ++t){
            f32x4 z = {};
            z = __builtin_amdgcn_mfma_f32_16x16x32_f16(kf[t][0], qf[0], z, 0, 0, 0);
            z = __builtin_amdgcn_mfma_f32_16x16x32_f16(kf[t][1], qf[1], z, 0, 0, 0);
            s[t] = z;
        }
        // ---- exp + tiled sums (lane: q = q0+l16, k = k0+16t+4g+r)
        half4_t pf[4];
        float ts[4];
        #pragma unroll
        for (int t = 0; t < 4; ++t){
            float e0 = __expf(s[t][0]*sm + bm);
            float e1 = __expf(s[t][1]*sm + bm);
            float e2 = __expf(s[t][2]*sm + bm);
            float e3 = __expf(s[t][3]*sm + bm);
            ts[t] = (e0 + e1) + (e2 + e3);
            pf[t][0]=(_Float16)e0; pf[t][1]=(_Float16)e1;
            pf[t][2]=(_Float16)e2; pf[t][3]=(_Float16)e3;
        }
        lsum += (ts[0] + ts[1]) + (ts[2] + ts[3]);
        // ---- PV: 16 MFMAs over 4 independent accumulators
        #pragma unroll
        for (int t = 0; t < 4; ++t)
            #pragma unroll
            for (int c = 0; c < 4; ++c)
                acc[c] = __builtin_amdgcn_mfma_f32_16x16x16f16(pf[t], vf[t][c], acc[c], 0, 0, 0);
    }
    // row denominators: lane's lsum covers q=l16; reduce over g groups
    lsum += __shfl_xor(lsum, 16, 64);
    lsum += __shfl_xor(lsum, 32, 64);
    if (g == 0) Ldenom[(size_t)bh*SEQ + q0 + l16] = lsum;
    const float inv = 1.0f / lsum;        // for q = l16
    float invr[4];
    #pragma unroll
    for (int r = 0; r < 4; ++r)
        invr[r] = __shfl(inv, 4*g + r, 64);   // redistribute to q = 4g+r rows
    // store: acc row = q0+4g+r, col = h*64 + 16c + l16
    #pragma unroll
    for (int c = 0; c < 4; ++c)
        #pragma unroll
        for (int r = 0; r < 4; ++r)
            attended[(size_t)(b*SEQ + q0 + 4*g + r)*EMB + h*64 + 16*c + l16]
                = (_Float16)(acc[c][r] * invr[r]);
}

// ------------------------------------------- pass 2: softmax mean over heads
// One block per (b, 16 q-rows, 256 k-cols): 4 waves x 64 k. Heads unrolled x2
// with hoisted Q-frags: 8 independent QK chains per step. No LDS, no barriers.
__global__ __launch_bounds__(256) void mean_kernel(
    const _Float16* __restrict__ Qp, const _Float16* __restrict__ Kp,
    const float* __restrict__ emo_bias, const float* __restrict__ modv,
    const float* __restrict__ Ldenom, float* __restrict__ mean_out)
{
    const int tid  = threadIdx.x;
    const int w    = tid >> 6;
    const int lane = tid & 63;
    const int l16  = lane & 15;
    const int g    = lane >> 4;
    // 4096 blocks, bijective XCD swizzle; work = b*1024 + ky*128 + qt
    const int n    = blockIdx.x;
    const int work = (n & 7)*512 + (n >> 3);
    const int b    = work >> 10;
    const int ky   = (work >> 7) & 7;
    const int qt   = work & 127;
    const int q0   = qt * 16;
    const int k0w  = ky*256 + w*64;

    const float mod = modv[b];
    const float sm  = 0.125f * mod;

    f32x4 msum[4] = {};                    // [j]: k = k0w + j*16 + l16, q = q0 + 4g + r
    for (int hp = 0; hp < HEADS/2; ++hp){
        const int h0 = 2*hp, h1 = 2*hp + 1;
        const size_t ho0 = (size_t)(b*HEADS + h0) * SEQ;
        const size_t ho1 = (size_t)(b*HEADS + h1) * SEQ;
        const float bm0 = emo_bias[h0] * mod;
        const float bm1 = emo_bias[h1] * mod;
        half8_t qa0 = *(const half8_t*)(Qp + (ho0 + q0 + l16)*HD + 8*g);
        half8_t qa1 = *(const half8_t*)(Qp + (ho0 + q0 + l16)*HD + 32 + 8*g);
        half8_t qb0 = *(const half8_t*)(Qp + (ho1 + q0 + l16)*HD + 8*g);
        half8_t qb1 = *(const half8_t*)(Qp + (ho1 + q0 + l16)*HD + 32 + 8*g);
        float iA[4], iB[4];
        #pragma unroll
        for (int r = 0; r < 4; ++r){
            iA[r] = 1.0f / Ldenom[ho0 + q0 + 4*g + r];
            iB[r] = 1.0f / Ldenom[ho1 + q0 + 4*g + r];
        }
        #pragma unroll
        for (int j = 0; j < 4; ++j){
            const int k0 = k0w + j*16;
            half8_t ka0 = *(const half8_t*)(Kp + (ho0 + k0 + l16)*HD + 8*g);
            half8_t ka1 = *(const half8_t*)(Kp + (ho0 + k0 + l16)*HD + 32 + 8*g);
            half8_t kb0 = *(const half8_t*)(Kp + (ho1 + k0 + l16)*HD + 8*g);
            half8_t kb1 = *(const half8_t*)(Kp + (ho1 + k0 + l16)*HD + 32 + 8*g);
            f32x4 sA = {}, sB = {};
            sA = __builtin_amdgcn_mfma_f32_16x16x32_f16(qa0, ka0, sA, 0, 0, 0);
            sA = __builtin_amdgcn_mfma_f32_16x16x32_f16(qa1, ka1, sA, 0, 0, 0);
            sB = __builtin_amdgcn_mfma_f32_16x16x32_f16(qb0, kb0, sB, 0, 0, 0);
            sB = __builtin_amdgcn_mfma_f32_16x16x32_f16(qb1, kb1, sB, 0, 0, 0);
            #pragma unroll
            for (int r = 0; r < 4; ++r){
                float pa = __expf(sA[r]*sm + bm0) * iA[r];
                float pb = __expf(sB[r]*sm + bm1) * iB[r];
                msum[j][r] += pa + pb;
            }
        }
    }
    #pragma unroll
    for (int j = 0; j < 4; ++j)
        #pragma unroll
        for (int r = 0; r < 4; ++r)
            mean_out[(size_t)(b*SEQ + q0 + 4*g + r)*SEQ + k0w + j*16 + l16]
                = msum[j][r] * (1.0f/HEADS);
}

// ------------------------------------------------------ output projection f32
__global__ __launch_bounds__(256) void outproj_kernel(
    const _Float16* __restrict__ A, const float* __restrict__ W,
    const float* __restrict__ bias, float* __restrict__ out)
{
    const int tid  = threadIdx.x;
    const int wid  = tid >> 6;
    const int lane = tid & 63;
    const int l16  = lane & 15;
    const int g    = lane >> 4;
    const int m0 = blockIdx.x*64 + (wid >> 1)*32;
    const int n0 = blockIdx.y*64 + (wid & 1)*32;

    f32x4 acc[2][2] = {};
    for (int kk = 0; kk < 8; ++kk){
        half8_t a[2][2], bb[2][2];
        #pragma unroll
        for (int u = 0; u < 2; ++u){
            const int k0 = kk*64 + u*32 + 8*g;
            #pragma unroll
            for (int i = 0; i < 2; ++i){
                a[u][i]  = *(const half8_t*)(A + (size_t)(m0 + i*16 + l16)*EMB + k0);
                bb[u][i] = cvt8(W + (size_t)(n0 + i*16 + l16)*EMB + k0);
            }
        }
        #pragma unroll
        for (int u = 0; u < 2; ++u)
            #pragma unroll
            for (int i = 0; i < 2; ++i)
                #pragma unroll
                for (int j = 0; j < 2; ++j)
                    acc[i][j] = __builtin_amdgcn_mfma_f32_16x16x32_f16(a[u][i], bb[u][j], acc[i][j], 0, 0, 0);
    }
    #pragma unroll
    for (int j = 0; j < 2; ++j){
        const int n = n0 + j*16 + l16;
        const float bn = bias[n];
        #pragma unroll
        for (int i = 0; i < 2; ++i)
            #pragma unroll
            for (int r = 0; r < 4; ++r){
                const int m = m0 + i*16 + 4*g + r;
                out[(size_t)m*EMB + n] = acc[i][j][r] + bn;
            }
    }
}

// ---------------------------------------------------------------------- host
extern "C" void kernel_launch(void* const* d_in, const int* in_sizes, int n_in,
                              void* d_out, int out_size, void* d_ws, size_t ws_size,
                              hipStream_t stream)
{
    const float* query = (const float*)d_in[0];
    const float* key_  = (const float*)d_in[1];
    const float* value = (const float*)d_in[2];
    const float* emo   = (const float*)d_in[3];
    const float* Wq = (const float*)d_in[4];
    const float* bq = (const float*)d_in[5];
    const float* Wk = (const float*)d_in[6];
    const float* bk = (const float*)d_in[7];
    const float* Wv = (const float*)d_in[8];
    const float* bv = (const float*)d_in[9];
    const float* Wo = (const float*)d_in[10];
    const float* bo = (const float*)d_in[11];
    const float* emo_bias = (const float*)d_in[12];

    const size_t NTOK = (size_t)BATCH * SEQ * EMB;   // 4,194,304
    _Float16* ws       = (_Float16*)d_ws;
    _Float16* Qp       = ws;                          // ws usage: exactly 32 MiB
    _Float16* Kp       = ws + NTOK;
    _Float16* Vt       = ws + 2*NTOK;
    _Float16* attended = ws + 3*NTOK;

    float* out0     = (float*)d_out;
    float* mean_out = out0 + NTOK;
    // Small scratch lives in the output-0 region (16 MB): written/read by the
    // early kernels, fully overwritten by outproj_kernel at the end.
    float* Ldenom   = out0;                           // BATCH*HEADS*SEQ = 65536 f32
    float* modv     = out0 + (size_t)BATCH*HEADS*SEQ; // 4 f32

    mod_kernel<<<1, 64, 0, stream>>>(emo, modv);
    dim3 pg(128, 8, 3);
    qkv_kernel<<<pg, 256, 0, stream>>>(query, key_, value, Wq, Wk, Wv,
                                       bq, bk, bv, Qp, Kp, Vt);
    pv_kernel<<<BATCH*HEADS*(SEQ/64), 256, 0, stream>>>(Qp, Kp, Vt, emo_bias, modv, attended, Ldenom);
    mean_kernel<<<BATCH*(SEQ/16)*(SEQ/256), 256, 0, stream>>>(Qp, Kp, emo_bias, modv, Ldenom, mean_out);
    outproj_kernel<<<dim3(128, 8), 256, 0, stream>>>(attended, Wo, bo, out0);
}

// Round 6
// 368.644 us; speedup vs baseline: 1.9786x; 1.9365x over previous
//
#include <hip/hip_runtime.h>

#define BATCH 4
#define SEQ   2048
#define EMB   512
#define HEADS 8
#define HD    64

typedef _Float16 half4_t __attribute__((ext_vector_type(4)));
typedef _Float16 half8_t __attribute__((ext_vector_type(8)));
typedef float    f32x4   __attribute__((ext_vector_type(4)));

// ---------------------------------------------------------------- mod factor
__global__ void mod_kernel(const float* __restrict__ emo, float* __restrict__ modv){
    int lane = threadIdx.x;                 // 64 threads, 1 wave
    for (int b = 0; b < BATCH; ++b){
        float v = emo[b*64 + lane];
        #pragma unroll
        for (int off = 32; off >= 1; off >>= 1) v += __shfl_xor(v, off, 64);
        if (lane == 0){
            float mean = v * (1.0f/64.0f);
            float sig  = 1.0f/(1.0f + __expf(-mean));
            modv[b] = 0.5f + 0.5f*sig;
        }
    }
}

__device__ inline half8_t cvt8(const float* p){
    float4 v0 = *(const float4*)p;
    float4 v1 = *(const float4*)(p + 4);
    half8_t r;
    r[0]=(_Float16)v0.x; r[1]=(_Float16)v0.y; r[2]=(_Float16)v0.z; r[3]=(_Float16)v0.w;
    r[4]=(_Float16)v1.x; r[5]=(_Float16)v1.y; r[6]=(_Float16)v1.z; r[7]=(_Float16)v1.w;
    return r;
}

// --------------------------------------- QKV projections, one launch (z=0,1,2)
// 64x64 block tile, 4 waves of 32x32, k-unrolled x2.
// Outputs are FRAGMENT-MAJOR so the attention kernels load wave-linear:
//  z=0,1 (Q,K; MFMA A-frag): chunk(bh, s>>4, c=d>>5) of 512 f16,
//        offset (((d>>3)&3)*16 + (s&15))*8 + (d&7)   [lane*8 + j]
//  z=2   (V; 16x16x16 B-frag): chunk(bh, s>>4, c=d>>4) of 256 f16,
//        offset (((s>>2)&3)*16 + (d&15))*4 + (s&3)   [lane*4 + i]
__global__ __launch_bounds__(256) void qkv_kernel(
    const float* __restrict__ X0, const float* __restrict__ X1, const float* __restrict__ X2,
    const float* __restrict__ W0, const float* __restrict__ W1, const float* __restrict__ W2,
    const float* __restrict__ b0, const float* __restrict__ b1, const float* __restrict__ b2,
    _Float16* __restrict__ o0, _Float16* __restrict__ o1, _Float16* __restrict__ o2)
{
    const int z = blockIdx.z;
    const float* X    = (z==0) ? X0 : (z==1) ? X1 : X2;
    const float* W    = (z==0) ? W0 : (z==1) ? W1 : W2;
    const float* bias = (z==0) ? b0 : (z==1) ? b1 : b2;
    _Float16*  out    = (z==0) ? o0 : (z==1) ? o1 : o2;

    const int tid  = threadIdx.x;
    const int wid  = tid >> 6;
    const int lane = tid & 63;
    const int l16  = lane & 15;
    const int g    = lane >> 4;
    const int m0 = blockIdx.x*64 + (wid >> 1)*32;
    const int n0 = blockIdx.y*64 + (wid & 1)*32;

    f32x4 acc[2][2] = {};
    for (int kk = 0; kk < 8; ++kk){         // 2 x 32-k chunks per iteration
        half8_t a[2][2], bb[2][2];
        #pragma unroll
        for (int u = 0; u < 2; ++u){
            const int k0 = kk*64 + u*32 + 8*g;
            #pragma unroll
            for (int i = 0; i < 2; ++i){
                a[u][i]  = cvt8(X + (size_t)(m0 + i*16 + l16)*EMB + k0);
                bb[u][i] = cvt8(W + (size_t)(n0 + i*16 + l16)*EMB + k0);
            }
        }
        #pragma unroll
        for (int u = 0; u < 2; ++u)
            #pragma unroll
            for (int i = 0; i < 2; ++i)
                #pragma unroll
                for (int j = 0; j < 2; ++j)
                    acc[i][j] = __builtin_amdgcn_mfma_f32_16x16x32_f16(a[u][i], bb[u][j], acc[i][j], 0, 0, 0);
    }
    #pragma unroll
    for (int jn = 0; jn < 2; ++jn){
        const int nn  = n0 + jn*16 + l16;
        const float bn = bias[nn];
        const int h = nn >> 6, d = nn & 63;
        #pragma unroll
        for (int i = 0; i < 2; ++i){
            #pragma unroll
            for (int r = 0; r < 4; ++r){
                const int m  = m0 + i*16 + 4*g + r;
                const int bb2 = m >> 11, s = m & 2047;
                const int bh  = bb2*8 + h;
                const float v = acc[i][jn][r] + bn;
                size_t idx;
                if (z == 2)
                    idx = ((size_t)(bh*128 + (s>>4))*4 + (d>>4))*256
                        + (size_t)((((s>>2)&3)*16 + (d&15))*4 + (s&3));
                else
                    idx = ((size_t)(bh*128 + (s>>4))*2 + (d>>5))*512
                        + (size_t)((((d>>3)&3)*16 + (s&15))*8 + (d&7));
                out[idx] = (_Float16)v;
            }
        }
    }
}

// ---------------------------------------------------- pass 1: PV + denominators
// One block per (b,h,64 q-rows): 4 waves x 16 q-rows. K-loop x4 (64 keys/iter).
// All Q/K/V loads are fragment-major: contiguous per lane, fully coalesced.
__global__ __launch_bounds__(256) void pv_kernel(
    const _Float16* __restrict__ Qf, const _Float16* __restrict__ Kf,
    const _Float16* __restrict__ Vf, const float* __restrict__ emo_bias,
    const float* __restrict__ modv, _Float16* __restrict__ attended,
    float* __restrict__ Ldenom)
{
    const int tid  = threadIdx.x;
    const int w    = tid >> 6;
    const int lane = tid & 63;
    const int l16  = lane & 15;
    const int g    = lane >> 4;
    // bijective XCD swizzle for 1024 blocks: 8 XCDs x 128
    const int n    = blockIdx.x;
    const int work = (n & 7)*128 + (n >> 3);
    const int qt   = work & 31;           // SEQ/64 = 32 q-tiles
    const int bh   = work >> 5;           // in [0,32)
    const int b    = bh >> 3, h = bh & 7;
    const int q0   = qt*64 + w*16;

    const float mod = modv[b];
    const float sm  = 0.125f * mod;
    const float bm  = emo_bias[h] * mod;

    const size_t fB = (size_t)bh * 128;   // fragment-chunk row base

    half8_t qf[2];
    #pragma unroll
    for (int c = 0; c < 2; ++c)
        qf[c] = *(const half8_t*)(Qf + ((fB + (q0>>4))*2 + c)*512 + lane*8);

    f32x4 acc[4] = {};
    float lsum = 0.f;
    for (int kt = 0; kt < SEQ/64; ++kt){
        const int kt4 = kt*4;
        // ---- issue all loads for 4 K-tiles (8 K + 16 V), all wave-linear
        half8_t kf[4][2];
        half4_t vf[4][4];
        #pragma unroll
        for (int t = 0; t < 4; ++t){
            #pragma unroll
            for (int c = 0; c < 2; ++c)
                kf[t][c] = *(const half8_t*)(Kf + ((fB + kt4 + t)*2 + c)*512 + lane*8);
            #pragma unroll
            for (int c = 0; c < 4; ++c)
                vf[t][c] = *(const half4_t*)(Vf + ((fB + kt4 + t)*4 + c)*256 + lane*4);
        }
        // ---- 4 independent QK chains
        f32x4 s[4];
        #pragma unroll
        for (int t = 0; t < 4; ++t){
            f32x4 zz = {};
            zz = __builtin_amdgcn_mfma_f32_16x16x32_f16(kf[t][0], qf[0], zz, 0, 0, 0);
            zz = __builtin_amdgcn_mfma_f32_16x16x32_f16(kf[t][1], qf[1], zz, 0, 0, 0);
            s[t] = zz;
        }
        // ---- exp + tiled sums (lane: q = q0+l16, k = kt*64+16t+4g+r)
        half4_t pf[4];
        float ts[4];
        #pragma unroll
        for (int t = 0; t < 4; ++t){
            float e0 = __expf(s[t][0]*sm + bm);
            float e1 = __expf(s[t][1]*sm + bm);
            float e2 = __expf(s[t][2]*sm + bm);
            float e3 = __expf(s[t][3]*sm + bm);
            ts[t] = (e0 + e1) + (e2 + e3);
            pf[t][0]=(_Float16)e0; pf[t][1]=(_Float16)e1;
            pf[t][2]=(_Float16)e2; pf[t][3]=(_Float16)e3;
        }
        lsum += (ts[0] + ts[1]) + (ts[2] + ts[3]);
        // ---- PV: 16 MFMAs over 4 independent accumulators
        #pragma unroll
        for (int t = 0; t < 4; ++t)
            #pragma unroll
            for (int c = 0; c < 4; ++c)
                acc[c] = __builtin_amdgcn_mfma_f32_16x16x16f16(pf[t], vf[t][c], acc[c], 0, 0, 0);
    }
    // row denominators: lane's lsum covers q=l16; reduce over g groups
    lsum += __shfl_xor(lsum, 16, 64);
    lsum += __shfl_xor(lsum, 32, 64);
    if (g == 0) Ldenom[(size_t)bh*SEQ + q0 + l16] = lsum;
    const float inv = 1.0f / lsum;        // for q = l16
    float invr[4];
    #pragma unroll
    for (int r = 0; r < 4; ++r)
        invr[r] = __shfl(inv, 4*g + r, 64);   // redistribute to q = 4g+r rows
    // store: acc row = q0+4g+r, col = h*64 + 16c + l16 (row-major attended)
    #pragma unroll
    for (int c = 0; c < 4; ++c)
        #pragma unroll
        for (int r = 0; r < 4; ++r)
            attended[(size_t)(b*SEQ + q0 + 4*g + r)*EMB + h*64 + 16*c + l16]
                = (_Float16)(acc[c][r] * invr[r]);
}

// ------------------------------------------- pass 2: softmax mean over heads
// One block per (b, 16 q-rows, 256 k-cols): 4 waves x 64 k. Heads unrolled x2.
// Q/K loads fragment-major (wave-linear). No LDS, no barriers.
__global__ __launch_bounds__(256) void mean_kernel(
    const _Float16* __restrict__ Qf, const _Float16* __restrict__ Kf,
    const float* __restrict__ emo_bias, const float* __restrict__ modv,
    const float* __restrict__ Ldenom, float* __restrict__ mean_out)
{
    const int tid  = threadIdx.x;
    const int w    = tid >> 6;
    const int lane = tid & 63;
    const int l16  = lane & 15;
    const int g    = lane >> 4;
    // 4096 blocks, bijective XCD swizzle; work = b*1024 + ky*128 + qt
    const int n    = blockIdx.x;
    const int work = (n & 7)*512 + (n >> 3);
    const int b    = work >> 10;
    const int ky   = (work >> 7) & 7;
    const int qt   = work & 127;
    const int q0   = qt * 16;
    const int k0w  = ky*256 + w*64;

    const float mod = modv[b];
    const float sm  = 0.125f * mod;

    f32x4 msum[4] = {};                    // [j]: k = k0w + j*16 + l16, q = q0 + 4g + r
    for (int hp = 0; hp < HEADS/2; ++hp){
        const int h0 = 2*hp, h1 = 2*hp + 1;
        const size_t lo0 = (size_t)(b*HEADS + h0) * SEQ;   // Ldenom base
        const size_t lo1 = (size_t)(b*HEADS + h1) * SEQ;
        const size_t f0  = (size_t)(b*HEADS + h0) * 128;   // fragment base
        const size_t f1  = (size_t)(b*HEADS + h1) * 128;
        const float bm0 = emo_bias[h0] * mod;
        const float bm1 = emo_bias[h1] * mod;
        half8_t qa0 = *(const half8_t*)(Qf + ((f0 + (q0>>4))*2 + 0)*512 + lane*8);
        half8_t qa1 = *(const half8_t*)(Qf + ((f0 + (q0>>4))*2 + 1)*512 + lane*8);
        half8_t qb0 = *(const half8_t*)(Qf + ((f1 + (q0>>4))*2 + 0)*512 + lane*8);
        half8_t qb1 = *(const half8_t*)(Qf + ((f1 + (q0>>4))*2 + 1)*512 + lane*8);
        float iA[4], iB[4];
        #pragma unroll
        for (int r = 0; r < 4; ++r){
            iA[r] = 1.0f / Ldenom[lo0 + q0 + 4*g + r];
            iB[r] = 1.0f / Ldenom[lo1 + q0 + 4*g + r];
        }
        #pragma unroll
        for (int j = 0; j < 4; ++j){
            const int kc = (k0w >> 4) + j;
            half8_t ka0 = *(const half8_t*)(Kf + ((f0 + kc)*2 + 0)*512 + lane*8);
            half8_t ka1 = *(const half8_t*)(Kf + ((f0 + kc)*2 + 1)*512 + lane*8);
            half8_t kb0 = *(const half8_t*)(Kf + ((f1 + kc)*2 + 0)*512 + lane*8);
            half8_t kb1 = *(const half8_t*)(Kf + ((f1 + kc)*2 + 1)*512 + lane*8);
            f32x4 sA = {}, sB = {};
            sA = __builtin_amdgcn_mfma_f32_16x16x32_f16(qa0, ka0, sA, 0, 0, 0);
            sA = __builtin_amdgcn_mfma_f32_16x16x32_f16(qa1, ka1, sA, 0, 0, 0);
            sB = __builtin_amdgcn_mfma_f32_16x16x32_f16(qb0, kb0, sB, 0, 0, 0);
            sB = __builtin_amdgcn_mfma_f32_16x16x32_f16(qb1, kb1, sB, 0, 0, 0);
            #pragma unroll
            for (int r = 0; r < 4; ++r){
                float pa = __expf(sA[r]*sm + bm0) * iA[r];
                float pb = __expf(sB[r]*sm + bm1) * iB[r];
                msum[j][r] += pa + pb;
            }
        }
    }
    #pragma unroll
    for (int j = 0; j < 4; ++j)
        #pragma unroll
        for (int r = 0; r < 4; ++r)
            mean_out[(size_t)(b*SEQ + q0 + 4*g + r)*SEQ + k0w + j*16 + l16]
                = msum[j][r] * (1.0f/HEADS);
}

// ------------------------------------------------------ output projection f32
__global__ __launch_bounds__(256) void outproj_kernel(
    const _Float16* __restrict__ A, const float* __restrict__ W,
    const float* __restrict__ bias, float* __restrict__ out)
{
    const int tid  = threadIdx.x;
    const int wid  = tid >> 6;
    const int lane = tid & 63;
    const int l16  = lane & 15;
    const int g    = lane >> 4;
    const int m0 = blockIdx.x*64 + (wid >> 1)*32;
    const int n0 = blockIdx.y*64 + (wid & 1)*32;

    f32x4 acc[2][2] = {};
    for (int kk = 0; kk < 8; ++kk){
        half8_t a[2][2], bb[2][2];
        #pragma unroll
        for (int u = 0; u < 2; ++u){
            const int k0 = kk*64 + u*32 + 8*g;
            #pragma unroll
            for (int i = 0; i < 2; ++i){
                a[u][i]  = *(const half8_t*)(A + (size_t)(m0 + i*16 + l16)*EMB + k0);
                bb[u][i] = cvt8(W + (size_t)(n0 + i*16 + l16)*EMB + k0);
            }
        }
        #pragma unroll
        for (int u = 0; u < 2; ++u)
            #pragma unroll
            for (int i = 0; i < 2; ++i)
                #pragma unroll
                for (int j = 0; j < 2; ++j)
                    acc[i][j] = __builtin_amdgcn_mfma_f32_16x16x32_f16(a[u][i], bb[u][j], acc[i][j], 0, 0, 0);
    }
    #pragma unroll
    for (int j = 0; j < 2; ++j){
        const int n = n0 + j*16 + l16;
        const float bn = bias[n];
        #pragma unroll
        for (int i = 0; i < 2; ++i)
            #pragma unroll
            for (int r = 0; r < 4; ++r){
                const int m = m0 + i*16 + 4*g + r;
                out[(size_t)m*EMB + n] = acc[i][j][r] + bn;
            }
    }
}

// ---------------------------------------------------------------------- host
extern "C" void kernel_launch(void* const* d_in, const int* in_sizes, int n_in,
                              void* d_out, int out_size, void* d_ws, size_t ws_size,
                              hipStream_t stream)
{
    const float* query = (const float*)d_in[0];
    const float* key_  = (const float*)d_in[1];
    const float* value = (const float*)d_in[2];
    const float* emo   = (const float*)d_in[3];
    const float* Wq = (const float*)d_in[4];
    const float* bq = (const float*)d_in[5];
    const float* Wk = (const float*)d_in[6];
    const float* bk = (const float*)d_in[7];
    const float* Wv = (const float*)d_in[8];
    const float* bv = (const float*)d_in[9];
    const float* Wo = (const float*)d_in[10];
    const float* bo = (const float*)d_in[11];
    const float* emo_bias = (const float*)d_in[12];

    const size_t NTOK = (size_t)BATCH * SEQ * EMB;   // 4,194,304
    _Float16* ws       = (_Float16*)d_ws;
    _Float16* Qp       = ws;                          // ws usage: exactly 32 MiB
    _Float16* Kp       = ws + NTOK;
    _Float16* Vt       = ws + 2*NTOK;
    _Float16* attended = ws + 3*NTOK;

    float* out0     = (float*)d_out;
    float* mean_out = out0 + NTOK;
    // Small scratch lives in the output-0 region (16 MB): written/read by the
    // early kernels, fully overwritten by outproj_kernel at the end.
    float* Ldenom   = out0;                           // BATCH*HEADS*SEQ = 65536 f32
    float* modv     = out0 + (size_t)BATCH*HEADS*SEQ; // 4 f32

    mod_kernel<<<1, 64, 0, stream>>>(emo, modv);
    dim3 pg(128, 8, 3);
    qkv_kernel<<<pg, 256, 0, stream>>>(query, key_, value, Wq, Wk, Wv,
                                       bq, bk, bv, Qp, Kp, Vt);
    pv_kernel<<<BATCH*HEADS*(SEQ/64), 256, 0, stream>>>(Qp, Kp, Vt, emo_bias, modv, attended, Ldenom);
    mean_kernel<<<BATCH*(SEQ/16)*(SEQ/256), 256, 0, stream>>>(Qp, Kp, emo_bias, modv, Ldenom, mean_out);
    outproj_kernel<<<dim3(128, 8), 256, 0, stream>>>(attended, Wo, bo, out0);
}

// Round 7
// 227.102 us; speedup vs baseline: 3.2118x; 1.6232x over previous
//
#include <hip/hip_runtime.h>

#define BATCH 4
#define SEQ   2048
#define EMB   512
#define HEADS 8
#define HD    64

typedef _Float16 half4_t __attribute__((ext_vector_type(4)));
typedef _Float16 half8_t __attribute__((ext_vector_type(8)));
typedef float    f32x4   __attribute__((ext_vector_type(4)));

// ---------------------------------------------------------------- mod factor
__global__ void mod_kernel(const float* __restrict__ emo, float* __restrict__ modv){
    int lane = threadIdx.x;                 // 64 threads, 1 wave
    for (int b = 0; b < BATCH; ++b){
        float v = emo[b*64 + lane];
        #pragma unroll
        for (int off = 32; off >= 1; off >>= 1) v += __shfl_xor(v, off, 64);
        if (lane == 0){
            float mean = v * (1.0f/64.0f);
            float sig  = 1.0f/(1.0f + __expf(-mean));
            modv[b] = 0.5f + 0.5f*sig;
        }
    }
}

__device__ inline half8_t cvt8(const float* p){
    float4 v0 = *(const float4*)p;
    float4 v1 = *(const float4*)(p + 4);
    half8_t r;
    r[0]=(_Float16)v0.x; r[1]=(_Float16)v0.y; r[2]=(_Float16)v0.z; r[3]=(_Float16)v0.w;
    r[4]=(_Float16)v1.x; r[5]=(_Float16)v1.y; r[6]=(_Float16)v1.z; r[7]=(_Float16)v1.w;
    return r;
}

// --------------------------------------- QKV projections, one launch (z=0,1,2)
// LDS-staged GEMM: block = 128(m) x 64(n), BK=64, 4 waves of 64x32.
// LDS holds tiles in FRAGMENT-MAJOR order: [mtile][kchunk][frag_lane][8] so
// fragment reads are lane-linear (lane*16B, conflict-free); staging writes
// spread rows across all bank groups (floor rate).
// Outputs fragment-major for the attention kernels (same mapping as R6):
//  z=0,1 (Q,K; A-frag): ((bh*128+(s>>4))*2+(d>>5))*512 + (((d>>3)&3)*16+(s&15))*8 + (d&7)
//  z=2   (V; B-frag):   ((bh*128+(s>>4))*4+(d>>4))*256 + (((s>>2)&3)*16+(d&15))*4 + (s&3)
__global__ __launch_bounds__(256) void qkv_kernel(
    const float* __restrict__ X0, const float* __restrict__ X1, const float* __restrict__ X2,
    const float* __restrict__ W0, const float* __restrict__ W1, const float* __restrict__ W2,
    const float* __restrict__ b0, const float* __restrict__ b1, const float* __restrict__ b2,
    _Float16* __restrict__ o0, _Float16* __restrict__ o1, _Float16* __restrict__ o2)
{
    const int z = blockIdx.z;
    const float* X    = (z==0) ? X0 : (z==1) ? X1 : X2;
    const float* W    = (z==0) ? W0 : (z==1) ? W1 : W2;
    const float* bias = (z==0) ? b0 : (z==1) ? b1 : b2;
    _Float16*  out    = (z==0) ? o0 : (z==1) ? o1 : o2;

    __shared__ _Float16 lA[8*2*512];      // 16 KB: 8 mtiles x 2 kchunks x 1KB
    __shared__ _Float16 lB[4*2*512];      //  8 KB: 4 ntiles x 2 kchunks x 1KB

    const int tid  = threadIdx.x;
    const int wid  = tid >> 6;
    const int lane = tid & 63;
    const int l16  = lane & 15;
    const int g    = lane >> 4;
    const int mb = blockIdx.x;            // 128-row m-tile
    const int nb = blockIdx.y;            // 64-col n-tile
    const int wm = (wid >> 1)*64;         // wave m-offset
    const int wn = (wid & 1)*32;          // wave n-offset
    const int tR = tid >> 3;              // staging: row-in-pass (0..31)
    const int c8 = tid & 7;               // staging: 8-col chunk

    f32x4 acc[4][2] = {};
    for (int ks = 0; ks < 8; ++ks){
        __syncthreads();
        // ---- stage A: 128 rows x 64 k (f32->f16), fragment-major
        #pragma unroll
        for (int p = 0; p < 4; ++p){
            const int R = p*32 + tR;
            half8_t h = cvt8(X + (size_t)(mb*128 + R)*EMB + ks*64 + c8*8);
            *(half8_t*)(lA + ((size_t)((R>>4)*2 + (c8>>2)))*512
                           + ((c8&3)*16 + (R&15))*8) = h;
        }
        // ---- stage B: 64 rows x 64 k
        #pragma unroll
        for (int p = 0; p < 2; ++p){
            const int R = p*32 + tR;
            half8_t h = cvt8(W + (size_t)(nb*64 + R)*EMB + ks*64 + c8*8);
            *(half8_t*)(lB + ((size_t)((R>>4)*2 + (c8>>2)))*512
                           + ((c8&3)*16 + (R&15))*8) = h;
        }
        __syncthreads();
        // ---- compute: lane-linear frag reads + 16 MFMA
        #pragma unroll
        for (int u = 0; u < 2; ++u){
            half8_t af[4], bf[2];
            #pragma unroll
            for (int i = 0; i < 4; ++i)
                af[i] = *(half8_t*)(lA + ((size_t)(((wm>>4)+i)*2 + u))*512 + lane*8);
            #pragma unroll
            for (int j = 0; j < 2; ++j)
                bf[j] = *(half8_t*)(lB + ((size_t)(((wn>>4)+j)*2 + u))*512 + lane*8);
            #pragma unroll
            for (int i = 0; i < 4; ++i)
                #pragma unroll
                for (int j = 0; j < 2; ++j)
                    acc[i][j] = __builtin_amdgcn_mfma_f32_16x16x32_f16(af[i], bf[j], acc[i][j], 0, 0, 0);
        }
    }
    // ---- store (fragment-major out, mapping identical to R6)
    #pragma unroll
    for (int j = 0; j < 2; ++j){
        const int nn  = nb*64 + wn + j*16 + l16;
        const float bn = bias[nn];
        const int h = nn >> 6, d = nn & 63;
        #pragma unroll
        for (int i = 0; i < 4; ++i){
            #pragma unroll
            for (int r = 0; r < 4; ++r){
                const int m  = mb*128 + wm + i*16 + 4*g + r;
                const int bb2 = m >> 11, s = m & 2047;
                const int bh  = bb2*8 + h;
                const float v = acc[i][j][r] + bn;
                size_t idx;
                if (z == 2)
                    idx = ((size_t)(bh*128 + (s>>4))*4 + (d>>4))*256
                        + (size_t)((((s>>2)&3)*16 + (d&15))*4 + (s&3));
                else
                    idx = ((size_t)(bh*128 + (s>>4))*2 + (d>>5))*512
                        + (size_t)((((d>>3)&3)*16 + (s&15))*8 + (d&7));
                out[idx] = (_Float16)v;
            }
        }
    }
}

// ---------------------------------------------------- pass 1: PV + denominators
// (unchanged from R6 — verified)
__global__ __launch_bounds__(256) void pv_kernel(
    const _Float16* __restrict__ Qf, const _Float16* __restrict__ Kf,
    const _Float16* __restrict__ Vf, const float* __restrict__ emo_bias,
    const float* __restrict__ modv, _Float16* __restrict__ attended,
    float* __restrict__ Ldenom)
{
    const int tid  = threadIdx.x;
    const int w    = tid >> 6;
    const int lane = tid & 63;
    const int l16  = lane & 15;
    const int g    = lane >> 4;
    const int n    = blockIdx.x;
    const int work = (n & 7)*128 + (n >> 3);
    const int qt   = work & 31;
    const int bh   = work >> 5;
    const int b    = bh >> 3, h = bh & 7;
    const int q0   = qt*64 + w*16;

    const float mod = modv[b];
    const float sm  = 0.125f * mod;
    const float bm  = emo_bias[h] * mod;

    const size_t fB = (size_t)bh * 128;

    half8_t qf[2];
    #pragma unroll
    for (int c = 0; c < 2; ++c)
        qf[c] = *(const half8_t*)(Qf + ((fB + (q0>>4))*2 + c)*512 + lane*8);

    f32x4 acc[4] = {};
    float lsum = 0.f;
    for (int kt = 0; kt < SEQ/64; ++kt){
        const int kt4 = kt*4;
        half8_t kf[4][2];
        half4_t vf[4][4];
        #pragma unroll
        for (int t = 0; t < 4; ++t){
            #pragma unroll
            for (int c = 0; c < 2; ++c)
                kf[t][c] = *(const half8_t*)(Kf + ((fB + kt4 + t)*2 + c)*512 + lane*8);
            #pragma unroll
            for (int c = 0; c < 4; ++c)
                vf[t][c] = *(const half4_t*)(Vf + ((fB + kt4 + t)*4 + c)*256 + lane*4);
        }
        f32x4 s[4];
        #pragma unroll
        for (int t = 0; t < 4; ++t){
            f32x4 zz = {};
            zz = __builtin_amdgcn_mfma_f32_16x16x32_f16(kf[t][0], qf[0], zz, 0, 0, 0);
            zz = __builtin_amdgcn_mfma_f32_16x16x32_f16(kf[t][1], qf[1], zz, 0, 0, 0);
            s[t] = zz;
        }
        half4_t pf[4];
        float ts[4];
        #pragma unroll
        for (int t = 0; t < 4; ++t){
            float e0 = __expf(s[t][0]*sm + bm);
            float e1 = __expf(s[t][1]*sm + bm);
            float e2 = __expf(s[t][2]*sm + bm);
            float e3 = __expf(s[t][3]*sm + bm);
            ts[t] = (e0 + e1) + (e2 + e3);
            pf[t][0]=(_Float16)e0; pf[t][1]=(_Float16)e1;
            pf[t][2]=(_Float16)e2; pf[t][3]=(_Float16)e3;
        }
        lsum += (ts[0] + ts[1]) + (ts[2] + ts[3]);
        #pragma unroll
        for (int t = 0; t < 4; ++t)
            #pragma unroll
            for (int c = 0; c < 4; ++c)
                acc[c] = __builtin_amdgcn_mfma_f32_16x16x16f16(pf[t], vf[t][c], acc[c], 0, 0, 0);
    }
    lsum += __shfl_xor(lsum, 16, 64);
    lsum += __shfl_xor(lsum, 32, 64);
    if (g == 0) Ldenom[(size_t)bh*SEQ + q0 + l16] = lsum;
    const float inv = 1.0f / lsum;
    float invr[4];
    #pragma unroll
    for (int r = 0; r < 4; ++r)
        invr[r] = __shfl(inv, 4*g + r, 64);
    #pragma unroll
    for (int c = 0; c < 4; ++c)
        #pragma unroll
        for (int r = 0; r < 4; ++r)
            attended[(size_t)(b*SEQ + q0 + 4*g + r)*EMB + h*64 + 16*c + l16]
                = (_Float16)(acc[c][r] * invr[r]);
}

// ------------------------------------------- pass 2: softmax mean over heads
// (unchanged from R6 — verified)
__global__ __launch_bounds__(256) void mean_kernel(
    const _Float16* __restrict__ Qf, const _Float16* __restrict__ Kf,
    const float* __restrict__ emo_bias, const float* __restrict__ modv,
    const float* __restrict__ Ldenom, float* __restrict__ mean_out)
{
    const int tid  = threadIdx.x;
    const int w    = tid >> 6;
    const int lane = tid & 63;
    const int l16  = lane & 15;
    const int g    = lane >> 4;
    const int n    = blockIdx.x;
    const int work = (n & 7)*512 + (n >> 3);
    const int b    = work >> 10;
    const int ky   = (work >> 7) & 7;
    const int qt   = work & 127;
    const int q0   = qt * 16;
    const int k0w  = ky*256 + w*64;

    const float mod = modv[b];
    const float sm  = 0.125f * mod;

    f32x4 msum[4] = {};
    for (int hp = 0; hp < HEADS/2; ++hp){
        const int h0 = 2*hp, h1 = 2*hp + 1;
        const size_t lo0 = (size_t)(b*HEADS + h0) * SEQ;
        const size_t lo1 = (size_t)(b*HEADS + h1) * SEQ;
        const size_t f0  = (size_t)(b*HEADS + h0) * 128;
        const size_t f1  = (size_t)(b*HEADS + h1) * 128;
        const float bm0 = emo_bias[h0] * mod;
        const float bm1 = emo_bias[h1] * mod;
        half8_t qa0 = *(const half8_t*)(Qf + ((f0 + (q0>>4))*2 + 0)*512 + lane*8);
        half8_t qa1 = *(const half8_t*)(Qf + ((f0 + (q0>>4))*2 + 1)*512 + lane*8);
        half8_t qb0 = *(const half8_t*)(Qf + ((f1 + (q0>>4))*2 + 0)*512 + lane*8);
        half8_t qb1 = *(const half8_t*)(Qf + ((f1 + (q0>>4))*2 + 1)*512 + lane*8);
        float iA[4], iB[4];
        #pragma unroll
        for (int r = 0; r < 4; ++r){
            iA[r] = 1.0f / Ldenom[lo0 + q0 + 4*g + r];
            iB[r] = 1.0f / Ldenom[lo1 + q0 + 4*g + r];
        }
        #pragma unroll
        for (int j = 0; j < 4; ++j){
            const int kc = (k0w >> 4) + j;
            half8_t ka0 = *(const half8_t*)(Kf + ((f0 + kc)*2 + 0)*512 + lane*8);
            half8_t ka1 = *(const half8_t*)(Kf + ((f0 + kc)*2 + 1)*512 + lane*8);
            half8_t kb0 = *(const half8_t*)(Kf + ((f1 + kc)*2 + 0)*512 + lane*8);
            half8_t kb1 = *(const half8_t*)(Kf + ((f1 + kc)*2 + 1)*512 + lane*8);
            f32x4 sA = {}, sB = {};
            sA = __builtin_amdgcn_mfma_f32_16x16x32_f16(qa0, ka0, sA, 0, 0, 0);
            sA = __builtin_amdgcn_mfma_f32_16x16x32_f16(qa1, ka1, sA, 0, 0, 0);
            sB = __builtin_amdgcn_mfma_f32_16x16x32_f16(qb0, kb0, sB, 0, 0, 0);
            sB = __builtin_amdgcn_mfma_f32_16x16x32_f16(qb1, kb1, sB, 0, 0, 0);
            #pragma unroll
            for (int r = 0; r < 4; ++r){
                float pa = __expf(sA[r]*sm + bm0) * iA[r];
                float pb = __expf(sB[r]*sm + bm1) * iB[r];
                msum[j][r] += pa + pb;
            }
        }
    }
    #pragma unroll
    for (int j = 0; j < 4; ++j)
        #pragma unroll
        for (int r = 0; r < 4; ++r)
            mean_out[(size_t)(b*SEQ + q0 + 4*g + r)*SEQ + k0w + j*16 + l16]
                = msum[j][r] * (1.0f/HEADS);
}

// ------------------------------------------------- output projection (LDS GEMM)
// Same template as qkv: A = attended (f16, row-major), B = Wo (f32), C = f32.
__global__ __launch_bounds__(256) void outproj_kernel(
    const _Float16* __restrict__ A, const float* __restrict__ W,
    const float* __restrict__ bias, float* __restrict__ out)
{
    __shared__ _Float16 lA[8*2*512];
    __shared__ _Float16 lB[4*2*512];

    const int tid  = threadIdx.x;
    const int wid  = tid >> 6;
    const int lane = tid & 63;
    const int l16  = lane & 15;
    const int g    = lane >> 4;
    const int mb = blockIdx.x;
    const int nb = blockIdx.y;
    const int wm = (wid >> 1)*64;
    const int wn = (wid & 1)*32;
    const int tR = tid >> 3;
    const int c8 = tid & 7;

    f32x4 acc[4][2] = {};
    for (int ks = 0; ks < 8; ++ks){
        __syncthreads();
        #pragma unroll
        for (int p = 0; p < 4; ++p){
            const int R = p*32 + tR;
            half8_t h = *(const half8_t*)(A + (size_t)(mb*128 + R)*EMB + ks*64 + c8*8);
            *(half8_t*)(lA + ((size_t)((R>>4)*2 + (c8>>2)))*512
                           + ((c8&3)*16 + (R&15))*8) = h;
        }
        #pragma unroll
        for (int p = 0; p < 2; ++p){
            const int R = p*32 + tR;
            half8_t h = cvt8(W + (size_t)(nb*64 + R)*EMB + ks*64 + c8*8);
            *(half8_t*)(lB + ((size_t)((R>>4)*2 + (c8>>2)))*512
                           + ((c8&3)*16 + (R&15))*8) = h;
        }
        __syncthreads();
        #pragma unroll
        for (int u = 0; u < 2; ++u){
            half8_t af[4], bf[2];
            #pragma unroll
            for (int i = 0; i < 4; ++i)
                af[i] = *(half8_t*)(lA + ((size_t)(((wm>>4)+i)*2 + u))*512 + lane*8);
            #pragma unroll
            for (int j = 0; j < 2; ++j)
                bf[j] = *(half8_t*)(lB + ((size_t)(((wn>>4)+j)*2 + u))*512 + lane*8);
            #pragma unroll
            for (int i = 0; i < 4; ++i)
                #pragma unroll
                for (int j = 0; j < 2; ++j)
                    acc[i][j] = __builtin_amdgcn_mfma_f32_16x16x32_f16(af[i], bf[j], acc[i][j], 0, 0, 0);
        }
    }
    #pragma unroll
    for (int j = 0; j < 2; ++j){
        const int nn = nb*64 + wn + j*16 + l16;
        const float bn = bias[nn];
        #pragma unroll
        for (int i = 0; i < 4; ++i)
            #pragma unroll
            for (int r = 0; r < 4; ++r){
                const int m = mb*128 + wm + i*16 + 4*g + r;
                out[(size_t)m*EMB + nn] = acc[i][j][r] + bn;
            }
    }
}

// ---------------------------------------------------------------------- host
extern "C" void kernel_launch(void* const* d_in, const int* in_sizes, int n_in,
                              void* d_out, int out_size, void* d_ws, size_t ws_size,
                              hipStream_t stream)
{
    const float* query = (const float*)d_in[0];
    const float* key_  = (const float*)d_in[1];
    const float* value = (const float*)d_in[2];
    const float* emo   = (const float*)d_in[3];
    const float* Wq = (const float*)d_in[4];
    const float* bq = (const float*)d_in[5];
    const float* Wk = (const float*)d_in[6];
    const float* bk = (const float*)d_in[7];
    const float* Wv = (const float*)d_in[8];
    const float* bv = (const float*)d_in[9];
    const float* Wo = (const float*)d_in[10];
    const float* bo = (const float*)d_in[11];
    const float* emo_bias = (const float*)d_in[12];

    const size_t NTOK = (size_t)BATCH * SEQ * EMB;   // 4,194,304
    _Float16* ws       = (_Float16*)d_ws;
    _Float16* Qp       = ws;                          // ws usage: exactly 32 MiB
    _Float16* Kp       = ws + NTOK;
    _Float16* Vt       = ws + 2*NTOK;
    _Float16* attended = ws + 3*NTOK;

    float* out0     = (float*)d_out;
    float* mean_out = out0 + NTOK;
    float* Ldenom   = out0;                           // scratch in out0 region
    float* modv     = out0 + (size_t)BATCH*HEADS*SEQ; // overwritten by outproj

    mod_kernel<<<1, 64, 0, stream>>>(emo, modv);
    qkv_kernel<<<dim3(64, 8, 3), 256, 0, stream>>>(query, key_, value, Wq, Wk, Wv,
                                                   bq, bk, bv, Qp, Kp, Vt);
    pv_kernel<<<BATCH*HEADS*(SEQ/64), 256, 0, stream>>>(Qp, Kp, Vt, emo_bias, modv, attended, Ldenom);
    mean_kernel<<<BATCH*(SEQ/16)*(SEQ/256), 256, 0, stream>>>(Qp, Kp, emo_bias, modv, Ldenom, mean_out);
    outproj_kernel<<<dim3(64, 8), 256, 0, stream>>>(attended, Wo, bo, out0);
}

// Round 9
// 218.358 us; speedup vs baseline: 3.3405x; 1.0400x over previous
//
#include <hip/hip_runtime.h>

#define BATCH 4
#define SEQ   2048
#define EMB   512
#define HEADS 8
#define HD    64

typedef _Float16 half2_t __attribute__((ext_vector_type(2)));
typedef _Float16 half4_t __attribute__((ext_vector_type(4)));
typedef _Float16 half8_t __attribute__((ext_vector_type(8)));
typedef float    f32x4   __attribute__((ext_vector_type(4)));

#if __has_builtin(__builtin_amdgcn_exp2f)
#define EXP2F(x) __builtin_amdgcn_exp2f(x)
#else
#define EXP2F(x) exp2f(x)
#endif
#define LOG2E 1.44269504088896f

// packed f32x2 -> f16x2 (RTZ), bit-cast to our _Float16 vector type
#define PKRTZ(a, b) __builtin_bit_cast(half2_t, __builtin_amdgcn_cvt_pkrtz((a), (b)))

// ---------------------------------------------------------------- mod factor
__global__ void mod_kernel(const float* __restrict__ emo, float* __restrict__ modv){
    int lane = threadIdx.x;                 // 64 threads, 1 wave
    for (int b = 0; b < BATCH; ++b){
        float v = emo[b*64 + lane];
        #pragma unroll
        for (int off = 32; off >= 1; off >>= 1) v += __shfl_xor(v, off, 64);
        if (lane == 0){
            float mean = v * (1.0f/64.0f);
            float sig  = 1.0f/(1.0f + __expf(-mean));
            modv[b] = 0.5f + 0.5f*sig;
        }
    }
}

__device__ inline half8_t cvt8(const float* p){
    float4 v0 = *(const float4*)p;
    float4 v1 = *(const float4*)(p + 4);
    half8_t r;
    r[0]=(_Float16)v0.x; r[1]=(_Float16)v0.y; r[2]=(_Float16)v0.z; r[3]=(_Float16)v0.w;
    r[4]=(_Float16)v1.x; r[5]=(_Float16)v1.y; r[6]=(_Float16)v1.z; r[7]=(_Float16)v1.w;
    return r;
}

// --------------------------------------- QKV projections, one launch (z=0,1,2)
// (unchanged from R7 — verified)
__global__ __launch_bounds__(256) void qkv_kernel(
    const float* __restrict__ X0, const float* __restrict__ X1, const float* __restrict__ X2,
    const float* __restrict__ W0, const float* __restrict__ W1, const float* __restrict__ W2,
    const float* __restrict__ b0, const float* __restrict__ b1, const float* __restrict__ b2,
    _Float16* __restrict__ o0, _Float16* __restrict__ o1, _Float16* __restrict__ o2)
{
    const int z = blockIdx.z;
    const float* X    = (z==0) ? X0 : (z==1) ? X1 : X2;
    const float* W    = (z==0) ? W0 : (z==1) ? W1 : W2;
    const float* bias = (z==0) ? b0 : (z==1) ? b1 : b2;
    _Float16*  out    = (z==0) ? o0 : (z==1) ? o1 : o2;

    __shared__ _Float16 lA[8*2*512];      // 16 KB
    __shared__ _Float16 lB[4*2*512];      //  8 KB

    const int tid  = threadIdx.x;
    const int wid  = tid >> 6;
    const int lane = tid & 63;
    const int l16  = lane & 15;
    const int g    = lane >> 4;
    const int mb = blockIdx.x;
    const int nb = blockIdx.y;
    const int wm = (wid >> 1)*64;
    const int wn = (wid & 1)*32;
    const int tR = tid >> 3;
    const int c8 = tid & 7;

    f32x4 acc[4][2] = {};
    for (int ks = 0; ks < 8; ++ks){
        __syncthreads();
        #pragma unroll
        for (int p = 0; p < 4; ++p){
            const int R = p*32 + tR;
            half8_t h = cvt8(X + (size_t)(mb*128 + R)*EMB + ks*64 + c8*8);
            *(half8_t*)(lA + ((size_t)((R>>4)*2 + (c8>>2)))*512
                           + ((c8&3)*16 + (R&15))*8) = h;
        }
        #pragma unroll
        for (int p = 0; p < 2; ++p){
            const int R = p*32 + tR;
            half8_t h = cvt8(W + (size_t)(nb*64 + R)*EMB + ks*64 + c8*8);
            *(half8_t*)(lB + ((size_t)((R>>4)*2 + (c8>>2)))*512
                           + ((c8&3)*16 + (R&15))*8) = h;
        }
        __syncthreads();
        #pragma unroll
        for (int u = 0; u < 2; ++u){
            half8_t af[4], bf[2];
            #pragma unroll
            for (int i = 0; i < 4; ++i)
                af[i] = *(half8_t*)(lA + ((size_t)(((wm>>4)+i)*2 + u))*512 + lane*8);
            #pragma unroll
            for (int j = 0; j < 2; ++j)
                bf[j] = *(half8_t*)(lB + ((size_t)(((wn>>4)+j)*2 + u))*512 + lane*8);
            #pragma unroll
            for (int i = 0; i < 4; ++i)
                #pragma unroll
                for (int j = 0; j < 2; ++j)
                    acc[i][j] = __builtin_amdgcn_mfma_f32_16x16x32_f16(af[i], bf[j], acc[i][j], 0, 0, 0);
        }
    }
    #pragma unroll
    for (int j = 0; j < 2; ++j){
        const int nn  = nb*64 + wn + j*16 + l16;
        const float bn = bias[nn];
        const int h = nn >> 6, d = nn & 63;
        #pragma unroll
        for (int i = 0; i < 4; ++i){
            #pragma unroll
            for (int r = 0; r < 4; ++r){
                const int m  = mb*128 + wm + i*16 + 4*g + r;
                const int bb2 = m >> 11, s = m & 2047;
                const int bh  = bb2*8 + h;
                const float v = acc[i][j][r] + bn;
                size_t idx;
                if (z == 2)
                    idx = ((size_t)(bh*128 + (s>>4))*4 + (d>>4))*256
                        + (size_t)((((s>>2)&3)*16 + (d&15))*4 + (s&3));
                else
                    idx = ((size_t)(bh*128 + (s>>4))*2 + (d>>5))*512
                        + (size_t)((((d>>3)&3)*16 + (s&15))*8 + (d&7));
                out[idx] = (_Float16)v;
            }
        }
    }
}

// ---------------------------------------------------- pass 1: PV + denominators
// 32-key groups, explicit A/B register double-buffer (next group's 12 loads in
// flight across current group's compute). exp2-domain softmax (1 fma + 1 v_exp
// per element) + packed f16 converts. Index mappings identical to R7.
#define PV_LOADG(KF, VF, T) do {                                               \
    _Pragma("unroll")                                                          \
    for (int t_ = 0; t_ < 2; ++t_){                                            \
        _Pragma("unroll")                                                      \
        for (int c_ = 0; c_ < 2; ++c_)                                         \
            KF[t_][c_] = *(const half8_t*)(Kf + ((fB + (T) + t_)*2 + c_)*512 + lane*8); \
        _Pragma("unroll")                                                      \
        for (int c_ = 0; c_ < 4; ++c_)                                         \
            VF[t_][c_] = *(const half4_t*)(Vf + ((fB + (T) + t_)*4 + c_)*256 + lane*4); \
    }                                                                          \
} while(0)

#define PV_COMPG(KF, VF) do {                                                  \
    f32x4 s0_ = {}, s1_ = {};                                                  \
    s0_ = __builtin_amdgcn_mfma_f32_16x16x32_f16(KF[0][0], qf[0], s0_, 0,0,0); \
    s0_ = __builtin_amdgcn_mfma_f32_16x16x32_f16(KF[0][1], qf[1], s0_, 0,0,0); \
    s1_ = __builtin_amdgcn_mfma_f32_16x16x32_f16(KF[1][0], qf[0], s1_, 0,0,0); \
    s1_ = __builtin_amdgcn_mfma_f32_16x16x32_f16(KF[1][1], qf[1], s1_, 0,0,0); \
    float e0_ = EXP2F(s0_[0]*sm2 + bm2), e1_ = EXP2F(s0_[1]*sm2 + bm2);        \
    float e2_ = EXP2F(s0_[2]*sm2 + bm2), e3_ = EXP2F(s0_[3]*sm2 + bm2);        \
    float f0_ = EXP2F(s1_[0]*sm2 + bm2), f1_ = EXP2F(s1_[1]*sm2 + bm2);        \
    float f2_ = EXP2F(s1_[2]*sm2 + bm2), f3_ = EXP2F(s1_[3]*sm2 + bm2);        \
    lsum += ((e0_+e1_)+(e2_+e3_)) + ((f0_+f1_)+(f2_+f3_));                     \
    half2_t pl0_ = PKRTZ(e0_, e1_), ph0_ = PKRTZ(e2_, e3_);                    \
    half2_t pl1_ = PKRTZ(f0_, f1_), ph1_ = PKRTZ(f2_, f3_);                    \
    half4_t p0_ = __builtin_shufflevector(pl0_, ph0_, 0, 1, 2, 3);             \
    half4_t p1_ = __builtin_shufflevector(pl1_, ph1_, 0, 1, 2, 3);             \
    _Pragma("unroll")                                                          \
    for (int c_ = 0; c_ < 4; ++c_){                                            \
        acc[c_] = __builtin_amdgcn_mfma_f32_16x16x16f16(p0_, VF[0][c_], acc[c_], 0,0,0); \
        acc[c_] = __builtin_amdgcn_mfma_f32_16x16x16f16(p1_, VF[1][c_], acc[c_], 0,0,0); \
    }                                                                          \
} while(0)

__global__ __launch_bounds__(256) void pv_kernel(
    const _Float16* __restrict__ Qf, const _Float16* __restrict__ Kf,
    const _Float16* __restrict__ Vf, const float* __restrict__ emo_bias,
    const float* __restrict__ modv, _Float16* __restrict__ attended,
    float* __restrict__ Ldenom)
{
    const int tid  = threadIdx.x;
    const int w    = tid >> 6;
    const int lane = tid & 63;
    const int l16  = lane & 15;
    const int g    = lane >> 4;
    const int n    = blockIdx.x;
    const int work = (n & 7)*128 + (n >> 3);
    const int qt   = work & 31;
    const int bh   = work >> 5;
    const int b    = bh >> 3, h = bh & 7;
    const int q0   = qt*64 + w*16;

    const float mod = modv[b];
    const float sm2 = 0.125f * mod * LOG2E;
    const float bm2 = emo_bias[h] * mod * LOG2E;

    const size_t fB = (size_t)bh * 128;

    half8_t qf[2];
    #pragma unroll
    for (int c = 0; c < 2; ++c)
        qf[c] = *(const half8_t*)(Qf + ((fB + (q0>>4))*2 + c)*512 + lane*8);

    f32x4 acc[4] = {};
    float lsum = 0.f;

    half8_t kfA[2][2], kfB[2][2];
    half4_t vfA[2][4], vfB[2][4];
    PV_LOADG(kfA, vfA, 0);
    for (int gg = 0; gg < 64; gg += 2){
        PV_LOADG(kfB, vfB, (gg + 1)*2);
        PV_COMPG(kfA, vfA);
        if (gg < 62) PV_LOADG(kfA, vfA, (gg + 2)*2);
        PV_COMPG(kfB, vfB);
    }

    lsum += __shfl_xor(lsum, 16, 64);
    lsum += __shfl_xor(lsum, 32, 64);
    if (g == 0) Ldenom[(size_t)bh*SEQ + q0 + l16] = lsum;
    const float inv = 1.0f / lsum;
    float invr[4];
    #pragma unroll
    for (int r = 0; r < 4; ++r)
        invr[r] = __shfl(inv, 4*g + r, 64);
    #pragma unroll
    for (int c = 0; c < 4; ++c)
        #pragma unroll
        for (int r = 0; r < 4; ++r)
            attended[(size_t)(b*SEQ + q0 + 4*g + r)*EMB + h*64 + 16*c + l16]
                = (_Float16)(acc[c][r] * invr[r]);
}

// ------------------------------------------- pass 2: softmax mean over heads
// (R7 structure; exp2-domain softmax)
__global__ __launch_bounds__(256) void mean_kernel(
    const _Float16* __restrict__ Qf, const _Float16* __restrict__ Kf,
    const float* __restrict__ emo_bias, const float* __restrict__ modv,
    const float* __restrict__ Ldenom, float* __restrict__ mean_out)
{
    const int tid  = threadIdx.x;
    const int w    = tid >> 6;
    const int lane = tid & 63;
    const int l16  = lane & 15;
    const int g    = lane >> 4;
    const int n    = blockIdx.x;
    const int work = (n & 7)*512 + (n >> 3);
    const int b    = work >> 10;
    const int ky   = (work >> 7) & 7;
    const int qt   = work & 127;
    const int q0   = qt * 16;
    const int k0w  = ky*256 + w*64;

    const float mod = modv[b];
    const float sm2 = 0.125f * mod * LOG2E;

    f32x4 msum[4] = {};
    for (int hp = 0; hp < HEADS/2; ++hp){
        const int h0 = 2*hp, h1 = 2*hp + 1;
        const size_t lo0 = (size_t)(b*HEADS + h0) * SEQ;
        const size_t lo1 = (size_t)(b*HEADS + h1) * SEQ;
        const size_t f0  = (size_t)(b*HEADS + h0) * 128;
        const size_t f1  = (size_t)(b*HEADS + h1) * 128;
        const float bm20 = emo_bias[h0] * mod * LOG2E;
        const float bm21 = emo_bias[h1] * mod * LOG2E;
        half8_t qa0 = *(const half8_t*)(Qf + ((f0 + (q0>>4))*2 + 0)*512 + lane*8);
        half8_t qa1 = *(const half8_t*)(Qf + ((f0 + (q0>>4))*2 + 1)*512 + lane*8);
        half8_t qb0 = *(const half8_t*)(Qf + ((f1 + (q0>>4))*2 + 0)*512 + lane*8);
        half8_t qb1 = *(const half8_t*)(Qf + ((f1 + (q0>>4))*2 + 1)*512 + lane*8);
        float iA[4], iB[4];
        #pragma unroll
        for (int r = 0; r < 4; ++r){
            iA[r] = 1.0f / Ldenom[lo0 + q0 + 4*g + r];
            iB[r] = 1.0f / Ldenom[lo1 + q0 + 4*g + r];
        }
        #pragma unroll
        for (int j = 0; j < 4; ++j){
            const int kc = (k0w >> 4) + j;
            half8_t ka0 = *(const half8_t*)(Kf + ((f0 + kc)*2 + 0)*512 + lane*8);
            half8_t ka1 = *(const half8_t*)(Kf + ((f0 + kc)*2 + 1)*512 + lane*8);
            half8_t kb0 = *(const half8_t*)(Kf + ((f1 + kc)*2 + 0)*512 + lane*8);
            half8_t kb1 = *(const half8_t*)(Kf + ((f1 + kc)*2 + 1)*512 + lane*8);
            f32x4 sA = {}, sB = {};
            sA = __builtin_amdgcn_mfma_f32_16x16x32_f16(qa0, ka0, sA, 0, 0, 0);
            sA = __builtin_amdgcn_mfma_f32_16x16x32_f16(qa1, ka1, sA, 0, 0, 0);
            sB = __builtin_amdgcn_mfma_f32_16x16x32_f16(qb0, kb0, sB, 0, 0, 0);
            sB = __builtin_amdgcn_mfma_f32_16x16x32_f16(qb1, kb1, sB, 0, 0, 0);
            #pragma unroll
            for (int r = 0; r < 4; ++r){
                float pa = EXP2F(sA[r]*sm2 + bm20) * iA[r];
                float pb = EXP2F(sB[r]*sm2 + bm21) * iB[r];
                msum[j][r] += pa + pb;
            }
        }
    }
    #pragma unroll
    for (int j = 0; j < 4; ++j)
        #pragma unroll
        for (int r = 0; r < 4; ++r)
            mean_out[(size_t)(b*SEQ + q0 + 4*g + r)*SEQ + k0w + j*16 + l16]
                = msum[j][r] * (1.0f/HEADS);
}

// ------------------------------------------------- output projection (LDS GEMM)
// (unchanged from R7 — verified)
__global__ __launch_bounds__(256) void outproj_kernel(
    const _Float16* __restrict__ A, const float* __restrict__ W,
    const float* __restrict__ bias, float* __restrict__ out)
{
    __shared__ _Float16 lA[8*2*512];
    __shared__ _Float16 lB[4*2*512];

    const int tid  = threadIdx.x;
    const int wid  = tid >> 6;
    const int lane = tid & 63;
    const int l16  = lane & 15;
    const int g    = lane >> 4;
    const int mb = blockIdx.x;
    const int nb = blockIdx.y;
    const int wm = (wid >> 1)*64;
    const int wn = (wid & 1)*32;
    const int tR = tid >> 3;
    const int c8 = tid & 7;

    f32x4 acc[4][2] = {};
    for (int ks = 0; ks < 8; ++ks){
        __syncthreads();
        #pragma unroll
        for (int p = 0; p < 4; ++p){
            const int R = p*32 + tR;
            half8_t h = *(const half8_t*)(A + (size_t)(mb*128 + R)*EMB + ks*64 + c8*8);
            *(half8_t*)(lA + ((size_t)((R>>4)*2 + (c8>>2)))*512
                           + ((c8&3)*16 + (R&15))*8) = h;
        }
        #pragma unroll
        for (int p = 0; p < 2; ++p){
            const int R = p*32 + tR;
            half8_t h = cvt8(W + (size_t)(nb*64 + R)*EMB + ks*64 + c8*8);
            *(half8_t*)(lB + ((size_t)((R>>4)*2 + (c8>>2)))*512
                           + ((c8&3)*16 + (R&15))*8) = h;
        }
        __syncthreads();
        #pragma unroll
        for (int u = 0; u < 2; ++u){
            half8_t af[4], bf[2];
            #pragma unroll
            for (int i = 0; i < 4; ++i)
                af[i] = *(half8_t*)(lA + ((size_t)(((wm>>4)+i)*2 + u))*512 + lane*8);
            #pragma unroll
            for (int j = 0; j < 2; ++j)
                bf[j] = *(half8_t*)(lB + ((size_t)(((wn>>4)+j)*2 + u))*512 + lane*8);
            #pragma unroll
            for (int i = 0; i < 4; ++i)
                #pragma unroll
                for (int j = 0; j < 2; ++j)
                    acc[i][j] = __builtin_amdgcn_mfma_f32_16x16x32_f16(af[i], bf[j], acc[i][j], 0, 0, 0);
        }
    }
    #pragma unroll
    for (int j = 0; j < 2; ++j){
        const int nn = nb*64 + wn + j*16 + l16;
        const float bn = bias[nn];
        #pragma unroll
        for (int i = 0; i < 4; ++i)
            #pragma unroll
            for (int r = 0; r < 4; ++r){
                const int m = mb*128 + wm + i*16 + 4*g + r;
                out[(size_t)m*EMB + nn] = acc[i][j][r] + bn;
            }
    }
}

// ---------------------------------------------------------------------- host
extern "C" void kernel_launch(void* const* d_in, const int* in_sizes, int n_in,
                              void* d_out, int out_size, void* d_ws, size_t ws_size,
                              hipStream_t stream)
{
    const float* query = (const float*)d_in[0];
    const float* key_  = (const float*)d_in[1];
    const float* value = (const float*)d_in[2];
    const float* emo   = (const float*)d_in[3];
    const float* Wq = (const float*)d_in[4];
    const float* bq = (const float*)d_in[5];
    const float* Wk = (const float*)d_in[6];
    const float* bk = (const float*)d_in[7];
    const float* Wv = (const float*)d_in[8];
    const float* bv = (const float*)d_in[9];
    const float* Wo = (const float*)d_in[10];
    const float* bo = (const float*)d_in[11];
    const float* emo_bias = (const float*)d_in[12];

    const size_t NTOK = (size_t)BATCH * SEQ * EMB;   // 4,194,304
    _Float16* ws       = (_Float16*)d_ws;
    _Float16* Qp       = ws;                          // ws usage: exactly 32 MiB
    _Float16* Kp       = ws + NTOK;
    _Float16* Vt       = ws + 2*NTOK;
    _Float16* attended = ws + 3*NTOK;

    float* out0     = (float*)d_out;
    float* mean_out = out0 + NTOK;
    float* Ldenom   = out0;                           // scratch in out0 region
    float* modv     = out0 + (size_t)BATCH*HEADS*SEQ; // overwritten by outproj

    mod_kernel<<<1, 64, 0, stream>>>(emo, modv);
    qkv_kernel<<<dim3(64, 8, 3), 256, 0, stream>>>(query, key_, value, Wq, Wk, Wv,
                                                   bq, bk, bv, Qp, Kp, Vt);
    pv_kernel<<<BATCH*HEADS*(SEQ/64), 256, 0, stream>>>(Qp, Kp, Vt, emo_bias, modv, attended, Ldenom);
    mean_kernel<<<BATCH*(SEQ/16)*(SEQ/256), 256, 0, stream>>>(Qp, Kp, emo_bias, modv, Ldenom, mean_out);
    outproj_kernel<<<dim3(64, 8), 256, 0, stream>>>(attended, Wo, bo, out0);
}

// Round 10
// 194.032 us; speedup vs baseline: 3.7593x; 1.1254x over previous
//
#include <hip/hip_runtime.h>

#define BATCH 4
#define SEQ   2048
#define EMB   512
#define HEADS 8
#define HD    64

typedef _Float16 half2_t __attribute__((ext_vector_type(2)));
typedef _Float16 half4_t __attribute__((ext_vector_type(4)));
typedef _Float16 half8_t __attribute__((ext_vector_type(8)));
typedef float    f32x4   __attribute__((ext_vector_type(4)));

#if __has_builtin(__builtin_amdgcn_exp2f)
#define EXP2F(x) __builtin_amdgcn_exp2f(x)
#else
#define EXP2F(x) exp2f(x)
#endif
#define LOG2E 1.44269504088896f

#define PKRTZ(a, b) __builtin_bit_cast(half2_t, __builtin_amdgcn_cvt_pkrtz((a), (b)))

// ---------------------------------------------------------------- mod factor
__global__ void mod_kernel(const float* __restrict__ emo, float* __restrict__ modv){
    int lane = threadIdx.x;                 // 64 threads, 1 wave
    for (int b = 0; b < BATCH; ++b){
        float v = emo[b*64 + lane];
        #pragma unroll
        for (int off = 32; off >= 1; off >>= 1) v += __shfl_xor(v, off, 64);
        if (lane == 0){
            float mean = v * (1.0f/64.0f);
            float sig  = 1.0f/(1.0f + __expf(-mean));
            modv[b] = 0.5f + 0.5f*sig;
        }
    }
}

__device__ inline half8_t cvt8(const float* p){
    float4 v0 = *(const float4*)p;
    float4 v1 = *(const float4*)(p + 4);
    half8_t r;
    r[0]=(_Float16)v0.x; r[1]=(_Float16)v0.y; r[2]=(_Float16)v0.z; r[3]=(_Float16)v0.w;
    r[4]=(_Float16)v1.x; r[5]=(_Float16)v1.y; r[6]=(_Float16)v1.z; r[7]=(_Float16)v1.w;
    return r;
}

// --------------------------------------- QKV projections, one launch (z=0,1,2)
// Fragment-major outputs:
//  z=0,1 (Q,K; A-frag): ((bh*128+(s>>4))*2+(d>>5))*512 + (((d>>3)&3)*16+(s&15))*8 + (d&7)
//  z=2   (V; paired B-frag): ((bh*128+(s>>4))*2+(d>>5))*512
//        + (((s>>2)&3)*16+(d&15))*8 + ((d>>4)&1)*4 + (s&3)
//        (half8 elems 0-3 -> c=2p frag, 4-7 -> c=2p+1 frag)
__global__ __launch_bounds__(256) void qkv_kernel(
    const float* __restrict__ X0, const float* __restrict__ X1, const float* __restrict__ X2,
    const float* __restrict__ W0, const float* __restrict__ W1, const float* __restrict__ W2,
    const float* __restrict__ b0, const float* __restrict__ b1, const float* __restrict__ b2,
    _Float16* __restrict__ o0, _Float16* __restrict__ o1, _Float16* __restrict__ o2)
{
    const int z = blockIdx.z;
    const float* X    = (z==0) ? X0 : (z==1) ? X1 : X2;
    const float* W    = (z==0) ? W0 : (z==1) ? W1 : W2;
    const float* bias = (z==0) ? b0 : (z==1) ? b1 : b2;
    _Float16*  out    = (z==0) ? o0 : (z==1) ? o1 : o2;

    __shared__ _Float16 lA[8*2*512];      // 16 KB
    __shared__ _Float16 lB[4*2*512];      //  8 KB

    const int tid  = threadIdx.x;
    const int wid  = tid >> 6;
    const int lane = tid & 63;
    const int l16  = lane & 15;
    const int g    = lane >> 4;
    const int mb = blockIdx.x;
    const int nb = blockIdx.y;
    const int wm = (wid >> 1)*64;
    const int wn = (wid & 1)*32;
    const int tR = tid >> 3;
    const int c8 = tid & 7;

    f32x4 acc[4][2] = {};
    for (int ks = 0; ks < 8; ++ks){
        __syncthreads();
        #pragma unroll
        for (int p = 0; p < 4; ++p){
            const int R = p*32 + tR;
            half8_t h = cvt8(X + (size_t)(mb*128 + R)*EMB + ks*64 + c8*8);
            *(half8_t*)(lA + ((size_t)((R>>4)*2 + (c8>>2)))*512
                           + ((c8&3)*16 + (R&15))*8) = h;
        }
        #pragma unroll
        for (int p = 0; p < 2; ++p){
            const int R = p*32 + tR;
            half8_t h = cvt8(W + (size_t)(nb*64 + R)*EMB + ks*64 + c8*8);
            *(half8_t*)(lB + ((size_t)((R>>4)*2 + (c8>>2)))*512
                           + ((c8&3)*16 + (R&15))*8) = h;
        }
        __syncthreads();
        #pragma unroll
        for (int u = 0; u < 2; ++u){
            half8_t af[4], bf[2];
            #pragma unroll
            for (int i = 0; i < 4; ++i)
                af[i] = *(half8_t*)(lA + ((size_t)(((wm>>4)+i)*2 + u))*512 + lane*8);
            #pragma unroll
            for (int j = 0; j < 2; ++j)
                bf[j] = *(half8_t*)(lB + ((size_t)(((wn>>4)+j)*2 + u))*512 + lane*8);
            #pragma unroll
            for (int i = 0; i < 4; ++i)
                #pragma unroll
                for (int j = 0; j < 2; ++j)
                    acc[i][j] = __builtin_amdgcn_mfma_f32_16x16x32_f16(af[i], bf[j], acc[i][j], 0, 0, 0);
        }
    }
    #pragma unroll
    for (int j = 0; j < 2; ++j){
        const int nn  = nb*64 + wn + j*16 + l16;
        const float bn = bias[nn];
        const int h = nn >> 6, d = nn & 63;
        #pragma unroll
        for (int i = 0; i < 4; ++i){
            #pragma unroll
            for (int r = 0; r < 4; ++r){
                const int m  = mb*128 + wm + i*16 + 4*g + r;
                const int bb2 = m >> 11, s = m & 2047;
                const int bh  = bb2*8 + h;
                const float v = acc[i][j][r] + bn;
                size_t idx;
                if (z == 2)
                    idx = ((size_t)(bh*128 + (s>>4))*2 + (d>>5))*512
                        + (size_t)((((s>>2)&3)*16 + (d&15))*8 + ((d>>4)&1)*4 + (s&3));
                else
                    idx = ((size_t)(bh*128 + (s>>4))*2 + (d>>5))*512
                        + (size_t)((((d>>3)&3)*16 + (s&15))*8 + (d&7));
                out[idx] = (_Float16)v;
            }
        }
    }
}

// ---------------------------------------------------- pass 1: PV + denominators
// LDS-staged: per 64-key group the block stages K(8KB)+V(8KB) once (reg-staged,
// double-buffered, 1 barrier/group); 4 waves read fragments via lane-linear
// ds_read_b128 (conflict-free). Cuts per-CU L1 traffic 4x.
__global__ __launch_bounds__(256) void pv_kernel(
    const _Float16* __restrict__ Qf, const _Float16* __restrict__ Kf,
    const _Float16* __restrict__ Vf, const float* __restrict__ emo_bias,
    const float* __restrict__ modv, _Float16* __restrict__ attended,
    float* __restrict__ Ldenom)
{
    __shared__ _Float16 lK[2][4096];      // 2 x 8 KB (4 tiles x 2 chunks x 512)
    __shared__ _Float16 lV[2][4096];      // 2 x 8 KB (4 tiles x 2 pairs  x 512)

    const int tid  = threadIdx.x;
    const int lane = tid & 63;
    const int l16  = lane & 15;
    const int g    = lane >> 4;
    const int w    = tid >> 6;
    const int n    = blockIdx.x;
    const int work = (n & 7)*128 + (n >> 3);   // bijective for 1024 blocks
    const int qt   = work & 31;
    const int bh   = work >> 5;
    const int b    = bh >> 3, h = bh & 7;
    const int q0   = qt*64 + w*16;

    const float mod = modv[b];
    const float sm2 = 0.125f * mod * LOG2E;
    const float bm2 = emo_bias[h] * mod * LOG2E;

    const size_t fB = (size_t)bh * 128;

    half8_t qf[2];
    #pragma unroll
    for (int c = 0; c < 2; ++c)
        qf[c] = *(const half8_t*)(Qf + ((fB + (q0>>4))*2 + c)*512 + lane*8);

    // ---- prologue: stage group 0 (16 KB, 64B/thread)
    {
        const _Float16* gk = Kf + (fB)*1024 + tid*16;
        const _Float16* gv = Vf + (fB)*1024 + tid*16;
        *(half8_t*)(&lK[0][tid*16])     = *(const half8_t*)(gk);
        *(half8_t*)(&lK[0][tid*16 + 8]) = *(const half8_t*)(gk + 8);
        *(half8_t*)(&lV[0][tid*16])     = *(const half8_t*)(gv);
        *(half8_t*)(&lV[0][tid*16 + 8]) = *(const half8_t*)(gv + 8);
    }
    __syncthreads();

    f32x4 acc[4] = {};
    float lsum = 0.f;
    int cur = 0;
    for (int grp = 0; grp < SEQ/64; ++grp){
        // ---- issue next group's global loads early (latency hides under compute)
        half8_t rk0, rk1, rv0, rv1;
        if (grp < SEQ/64 - 1){
            const _Float16* gk = Kf + (fB + (size_t)(grp+1)*4)*1024 + tid*16;
            const _Float16* gv = Vf + (fB + (size_t)(grp+1)*4)*1024 + tid*16;
            rk0 = *(const half8_t*)(gk);
            rk1 = *(const half8_t*)(gk + 8);
            rv0 = *(const half8_t*)(gv);
            rv1 = *(const half8_t*)(gv + 8);
        }
        // ---- compute 4 k-tiles from LDS
        const _Float16* kb = &lK[cur][0];
        const _Float16* vb = &lV[cur][0];
        #pragma unroll
        for (int t = 0; t < 4; ++t){
            half8_t k0 = *(const half8_t*)(kb + (t*2+0)*512 + lane*8);
            half8_t k1 = *(const half8_t*)(kb + (t*2+1)*512 + lane*8);
            f32x4 s = {};
            s = __builtin_amdgcn_mfma_f32_16x16x32_f16(k0, qf[0], s, 0, 0, 0);
            s = __builtin_amdgcn_mfma_f32_16x16x32_f16(k1, qf[1], s, 0, 0, 0);
            float e0 = EXP2F(s[0]*sm2 + bm2);
            float e1 = EXP2F(s[1]*sm2 + bm2);
            float e2 = EXP2F(s[2]*sm2 + bm2);
            float e3 = EXP2F(s[3]*sm2 + bm2);
            lsum += (e0 + e1) + (e2 + e3);
            half2_t plo = PKRTZ(e0, e1), phi = PKRTZ(e2, e3);
            half4_t pf  = __builtin_shufflevector(plo, phi, 0, 1, 2, 3);
            half8_t vp0 = *(const half8_t*)(vb + (t*2+0)*512 + lane*8);
            half8_t vp1 = *(const half8_t*)(vb + (t*2+1)*512 + lane*8);
            half4_t v0 = __builtin_shufflevector(vp0, vp0, 0, 1, 2, 3);
            half4_t v1 = __builtin_shufflevector(vp0, vp0, 4, 5, 6, 7);
            half4_t v2 = __builtin_shufflevector(vp1, vp1, 0, 1, 2, 3);
            half4_t v3 = __builtin_shufflevector(vp1, vp1, 4, 5, 6, 7);
            acc[0] = __builtin_amdgcn_mfma_f32_16x16x16f16(pf, v0, acc[0], 0, 0, 0);
            acc[1] = __builtin_amdgcn_mfma_f32_16x16x16f16(pf, v1, acc[1], 0, 0, 0);
            acc[2] = __builtin_amdgcn_mfma_f32_16x16x16f16(pf, v2, acc[2], 0, 0, 0);
            acc[3] = __builtin_amdgcn_mfma_f32_16x16x16f16(pf, v3, acc[3], 0, 0, 0);
        }
        // ---- write next group into the free buffer (consumed pre-barrier last iter)
        if (grp < SEQ/64 - 1){
            _Float16* dk = &lK[cur^1][tid*16];
            _Float16* dv = &lV[cur^1][tid*16];
            *(half8_t*)(dk)     = rk0;
            *(half8_t*)(dk + 8) = rk1;
            *(half8_t*)(dv)     = rv0;
            *(half8_t*)(dv + 8) = rv1;
        }
        __syncthreads();
        cur ^= 1;
    }

    lsum += __shfl_xor(lsum, 16, 64);
    lsum += __shfl_xor(lsum, 32, 64);
    if (g == 0) Ldenom[(size_t)bh*SEQ + q0 + l16] = lsum;
    const float inv = 1.0f / lsum;
    float invr[4];
    #pragma unroll
    for (int r = 0; r < 4; ++r)
        invr[r] = __shfl(inv, 4*g + r, 64);
    #pragma unroll
    for (int c = 0; c < 4; ++c)
        #pragma unroll
        for (int r = 0; r < 4; ++r)
            attended[(size_t)(b*SEQ + q0 + 4*g + r)*EMB + h*64 + 16*c + l16]
                = (_Float16)(acc[c][r] * invr[r]);
}

// ------------------------------------------- pass 2: softmax mean over heads
// (unchanged from R9 — verified)
__global__ __launch_bounds__(256) void mean_kernel(
    const _Float16* __restrict__ Qf, const _Float16* __restrict__ Kf,
    const float* __restrict__ emo_bias, const float* __restrict__ modv,
    const float* __restrict__ Ldenom, float* __restrict__ mean_out)
{
    const int tid  = threadIdx.x;
    const int w    = tid >> 6;
    const int lane = tid & 63;
    const int l16  = lane & 15;
    const int g    = lane >> 4;
    const int n    = blockIdx.x;
    const int work = (n & 7)*512 + (n >> 3);
    const int b    = work >> 10;
    const int ky   = (work >> 7) & 7;
    const int qt   = work & 127;
    const int q0   = qt * 16;
    const int k0w  = ky*256 + w*64;

    const float mod = modv[b];
    const float sm2 = 0.125f * mod * LOG2E;

    f32x4 msum[4] = {};
    for (int hp = 0; hp < HEADS/2; ++hp){
        const int h0 = 2*hp, h1 = 2*hp + 1;
        const size_t lo0 = (size_t)(b*HEADS + h0) * SEQ;
        const size_t lo1 = (size_t)(b*HEADS + h1) * SEQ;
        const size_t f0  = (size_t)(b*HEADS + h0) * 128;
        const size_t f1  = (size_t)(b*HEADS + h1) * 128;
        const float bm20 = emo_bias[h0] * mod * LOG2E;
        const float bm21 = emo_bias[h1] * mod * LOG2E;
        half8_t qa0 = *(const half8_t*)(Qf + ((f0 + (q0>>4))*2 + 0)*512 + lane*8);
        half8_t qa1 = *(const half8_t*)(Qf + ((f0 + (q0>>4))*2 + 1)*512 + lane*8);
        half8_t qb0 = *(const half8_t*)(Qf + ((f1 + (q0>>4))*2 + 0)*512 + lane*8);
        half8_t qb1 = *(const half8_t*)(Qf + ((f1 + (q0>>4))*2 + 1)*512 + lane*8);
        float iA[4], iB[4];
        #pragma unroll
        for (int r = 0; r < 4; ++r){
            iA[r] = 1.0f / Ldenom[lo0 + q0 + 4*g + r];
            iB[r] = 1.0f / Ldenom[lo1 + q0 + 4*g + r];
        }
        #pragma unroll
        for (int j = 0; j < 4; ++j){
            const int kc = (k0w >> 4) + j;
            half8_t ka0 = *(const half8_t*)(Kf + ((f0 + kc)*2 + 0)*512 + lane*8);
            half8_t ka1 = *(const half8_t*)(Kf + ((f0 + kc)*2 + 1)*512 + lane*8);
            half8_t kb0 = *(const half8_t*)(Kf + ((f1 + kc)*2 + 0)*512 + lane*8);
            half8_t kb1 = *(const half8_t*)(Kf + ((f1 + kc)*2 + 1)*512 + lane*8);
            f32x4 sA = {}, sB = {};
            sA = __builtin_amdgcn_mfma_f32_16x16x32_f16(qa0, ka0, sA, 0, 0, 0);
            sA = __builtin_amdgcn_mfma_f32_16x16x32_f16(qa1, ka1, sA, 0, 0, 0);
            sB = __builtin_amdgcn_mfma_f32_16x16x32_f16(qb0, kb0, sB, 0, 0, 0);
            sB = __builtin_amdgcn_mfma_f32_16x16x32_f16(qb1, kb1, sB, 0, 0, 0);
            #pragma unroll
            for (int r = 0; r < 4; ++r){
                float pa = EXP2F(sA[r]*sm2 + bm20) * iA[r];
                float pb = EXP2F(sB[r]*sm2 + bm21) * iB[r];
                msum[j][r] += pa + pb;
            }
        }
    }
    #pragma unroll
    for (int j = 0; j < 4; ++j)
        #pragma unroll
        for (int r = 0; r < 4; ++r)
            mean_out[(size_t)(b*SEQ + q0 + 4*g + r)*SEQ + k0w + j*16 + l16]
                = msum[j][r] * (1.0f/HEADS);
}

// ------------------------------------------------- output projection (LDS GEMM)
// (unchanged from R7 — verified)
__global__ __launch_bounds__(256) void outproj_kernel(
    const _Float16* __restrict__ A, const float* __restrict__ W,
    const float* __restrict__ bias, float* __restrict__ out)
{
    __shared__ _Float16 lA[8*2*512];
    __shared__ _Float16 lB[4*2*512];

    const int tid  = threadIdx.x;
    const int wid  = tid >> 6;
    const int lane = tid & 63;
    const int l16  = lane & 15;
    const int g    = lane >> 4;
    const int mb = blockIdx.x;
    const int nb = blockIdx.y;
    const int wm = (wid >> 1)*64;
    const int wn = (wid & 1)*32;
    const int tR = tid >> 3;
    const int c8 = tid & 7;

    f32x4 acc[4][2] = {};
    for (int ks = 0; ks < 8; ++ks){
        __syncthreads();
        #pragma unroll
        for (int p = 0; p < 4; ++p){
            const int R = p*32 + tR;
            half8_t h = *(const half8_t*)(A + (size_t)(mb*128 + R)*EMB + ks*64 + c8*8);
            *(half8_t*)(lA + ((size_t)((R>>4)*2 + (c8>>2)))*512
                           + ((c8&3)*16 + (R&15))*8) = h;
        }
        #pragma unroll
        for (int p = 0; p < 2; ++p){
            const int R = p*32 + tR;
            half8_t h = cvt8(W + (size_t)(nb*64 + R)*EMB + ks*64 + c8*8);
            *(half8_t*)(lB + ((size_t)((R>>4)*2 + (c8>>2)))*512
                           + ((c8&3)*16 + (R&15))*8) = h;
        }
        __syncthreads();
        #pragma unroll
        for (int u = 0; u < 2; ++u){
            half8_t af[4], bf[2];
            #pragma unroll
            for (int i = 0; i < 4; ++i)
                af[i] = *(half8_t*)(lA + ((size_t)(((wm>>4)+i)*2 + u))*512 + lane*8);
            #pragma unroll
            for (int j = 0; j < 2; ++j)
                bf[j] = *(half8_t*)(lB + ((size_t)(((wn>>4)+j)*2 + u))*512 + lane*8);
            #pragma unroll
            for (int i = 0; i < 4; ++i)
                #pragma unroll
                for (int j = 0; j < 2; ++j)
                    acc[i][j] = __builtin_amdgcn_mfma_f32_16x16x32_f16(af[i], bf[j], acc[i][j], 0, 0, 0);
        }
    }
    #pragma unroll
    for (int j = 0; j < 2; ++j){
        const int nn = nb*64 + wn + j*16 + l16;
        const float bn = bias[nn];
        #pragma unroll
        for (int i = 0; i < 4; ++i)
            #pragma unroll
            for (int r = 0; r < 4; ++r){
                const int m = mb*128 + wm + i*16 + 4*g + r;
                out[(size_t)m*EMB + nn] = acc[i][j][r] + bn;
            }
    }
}

// ---------------------------------------------------------------------- host
extern "C" void kernel_launch(void* const* d_in, const int* in_sizes, int n_in,
                              void* d_out, int out_size, void* d_ws, size_t ws_size,
                              hipStream_t stream)
{
    const float* query = (const float*)d_in[0];
    const float* key_  = (const float*)d_in[1];
    const float* value = (const float*)d_in[2];
    const float* emo   = (const float*)d_in[3];
    const float* Wq = (const float*)d_in[4];
    const float* bq = (const float*)d_in[5];
    const float* Wk = (const float*)d_in[6];
    const float* bk = (const float*)d_in[7];
    const float* Wv = (const float*)d_in[8];
    const float* bv = (const float*)d_in[9];
    const float* Wo = (const float*)d_in[10];
    const float* bo = (const float*)d_in[11];
    const float* emo_bias = (const float*)d_in[12];

    const size_t NTOK = (size_t)BATCH * SEQ * EMB;   // 4,194,304
    _Float16* ws       = (_Float16*)d_ws;
    _Float16* Qp       = ws;                          // ws usage: exactly 32 MiB
    _Float16* Kp       = ws + NTOK;
    _Float16* Vt       = ws + 2*NTOK;
    _Float16* attended = ws + 3*NTOK;

    float* out0     = (float*)d_out;
    float* mean_out = out0 + NTOK;
    float* Ldenom   = out0;                           // scratch in out0 region
    float* modv     = out0 + (size_t)BATCH*HEADS*SEQ; // overwritten by outproj

    mod_kernel<<<1, 64, 0, stream>>>(emo, modv);
    qkv_kernel<<<dim3(64, 8, 3), 256, 0, stream>>>(query, key_, value, Wq, Wk, Wv,
                                                   bq, bk, bv, Qp, Kp, Vt);
    pv_kernel<<<BATCH*HEADS*(SEQ/64), 256, 0, stream>>>(Qp, Kp, Vt, emo_bias, modv, attended, Ldenom);
    mean_kernel<<<BATCH*(SEQ/16)*(SEQ/256), 256, 0, stream>>>(Qp, Kp, emo_bias, modv, Ldenom, mean_out);
    outproj_kernel<<<dim3(64, 8), 256, 0, stream>>>(attended, Wo, bo, out0);
}

// Round 11
// 177.162 us; speedup vs baseline: 4.1172x; 1.0952x over previous
//
#include <hip/hip_runtime.h>

#define BATCH 4
#define SEQ   2048
#define EMB   512
#define HEADS 8
#define HD    64

typedef _Float16 half2_t __attribute__((ext_vector_type(2)));
typedef _Float16 half4_t __attribute__((ext_vector_type(4)));
typedef _Float16 half8_t __attribute__((ext_vector_type(8)));
typedef float    f32x4   __attribute__((ext_vector_type(4)));

#if __has_builtin(__builtin_amdgcn_exp2f)
#define EXP2F(x) __builtin_amdgcn_exp2f(x)
#else
#define EXP2F(x) exp2f(x)
#endif
#define LOG2E 1.44269504088896f

#define PKRTZ(a, b) __builtin_bit_cast(half2_t, __builtin_amdgcn_cvt_pkrtz((a), (b)))

// ---------------------------------------------------------------- mod factor
__global__ void mod_kernel(const float* __restrict__ emo, float* __restrict__ modv){
    int lane = threadIdx.x;                 // 64 threads, 1 wave
    for (int b = 0; b < BATCH; ++b){
        float v = emo[b*64 + lane];
        #pragma unroll
        for (int off = 32; off >= 1; off >>= 1) v += __shfl_xor(v, off, 64);
        if (lane == 0){
            float mean = v * (1.0f/64.0f);
            float sig  = 1.0f/(1.0f + __expf(-mean));
            modv[b] = 0.5f + 0.5f*sig;
        }
    }
}

__device__ inline half8_t cvt8(const float* p){
    float4 v0 = *(const float4*)p;
    float4 v1 = *(const float4*)(p + 4);
    half8_t r;
    r[0]=(_Float16)v0.x; r[1]=(_Float16)v0.y; r[2]=(_Float16)v0.z; r[3]=(_Float16)v0.w;
    r[4]=(_Float16)v1.x; r[5]=(_Float16)v1.y; r[6]=(_Float16)v1.z; r[7]=(_Float16)v1.w;
    return r;
}

// --------------------------------------- QKV projections, one launch (z=0,1,2)
// LDS tiles now ROW-MAJOR with XOR-swizzled 16B chunks: logical chunk c of row
// R at physical chunk (c ^ (R&7)). Staging writes: each 8-lane row-group covers
// all 32 banks once -> 0 counted conflicts (was 8-way, 16.5M conflict cycles).
// Fragment reads: chunk (u*4+g)^(l16&7) -> lane-linear-equivalent distribution.
// Global fragment-major outputs unchanged (R10-verified):
//  z=0,1 (Q,K): ((bh*128+(s>>4))*2+(d>>5))*512 + (((d>>3)&3)*16+(s&15))*8 + (d&7)
//  z=2   (V):   ((bh*128+(s>>4))*2+(d>>5))*512 + (((s>>2)&3)*16+(d&15))*8 + ((d>>4)&1)*4 + (s&3)
__global__ __launch_bounds__(256) void qkv_kernel(
    const float* __restrict__ X0, const float* __restrict__ X1, const float* __restrict__ X2,
    const float* __restrict__ W0, const float* __restrict__ W1, const float* __restrict__ W2,
    const float* __restrict__ b0, const float* __restrict__ b1, const float* __restrict__ b2,
    _Float16* __restrict__ o0, _Float16* __restrict__ o1, _Float16* __restrict__ o2)
{
    const int z = blockIdx.z;
    const float* X    = (z==0) ? X0 : (z==1) ? X1 : X2;
    const float* W    = (z==0) ? W0 : (z==1) ? W1 : W2;
    const float* bias = (z==0) ? b0 : (z==1) ? b1 : b2;
    _Float16*  out    = (z==0) ? o0 : (z==1) ? o1 : o2;

    __shared__ _Float16 lA[128*64];       // 16 KB row-major, swizzled chunks
    __shared__ _Float16 lB[64*64];        //  8 KB

    const int tid  = threadIdx.x;
    const int wid  = tid >> 6;
    const int lane = tid & 63;
    const int l16  = lane & 15;
    const int g    = lane >> 4;
    const int l7   = l16 & 7;
    const int mb = blockIdx.x;
    const int nb = blockIdx.y;
    const int wm = (wid >> 1)*64;
    const int wn = (wid & 1)*32;
    const int tR = tid >> 3;
    const int c8 = tid & 7;

    f32x4 acc[4][2] = {};
    for (int ks = 0; ks < 8; ++ks){
        __syncthreads();
        #pragma unroll
        for (int p = 0; p < 4; ++p){
            const int R = p*32 + tR;
            half8_t h = cvt8(X + (size_t)(mb*128 + R)*EMB + ks*64 + c8*8);
            *(half8_t*)(lA + R*64 + ((c8 ^ (R & 7))*8)) = h;
        }
        #pragma unroll
        for (int p = 0; p < 2; ++p){
            const int R = p*32 + tR;
            half8_t h = cvt8(W + (size_t)(nb*64 + R)*EMB + ks*64 + c8*8);
            *(half8_t*)(lB + R*64 + ((c8 ^ (R & 7))*8)) = h;
        }
        __syncthreads();
        #pragma unroll
        for (int u = 0; u < 2; ++u){
            half8_t af[4], bf[2];
            #pragma unroll
            for (int i = 0; i < 4; ++i){
                const int rA = wm + i*16 + l16;
                af[i] = *(half8_t*)(lA + rA*64 + (((u*4 + g) ^ l7)*8));
            }
            #pragma unroll
            for (int j = 0; j < 2; ++j){
                const int rB = wn + j*16 + l16;
                bf[j] = *(half8_t*)(lB + rB*64 + (((u*4 + g) ^ l7)*8));
            }
            #pragma unroll
            for (int i = 0; i < 4; ++i)
                #pragma unroll
                for (int j = 0; j < 2; ++j)
                    acc[i][j] = __builtin_amdgcn_mfma_f32_16x16x32_f16(af[i], bf[j], acc[i][j], 0, 0, 0);
        }
    }
    #pragma unroll
    for (int j = 0; j < 2; ++j){
        const int nn  = nb*64 + wn + j*16 + l16;
        const float bn = bias[nn];
        const int h = nn >> 6, d = nn & 63;
        #pragma unroll
        for (int i = 0; i < 4; ++i){
            #pragma unroll
            for (int r = 0; r < 4; ++r){
                const int m  = mb*128 + wm + i*16 + 4*g + r;
                const int bb2 = m >> 11, s = m & 2047;
                const int bh  = bb2*8 + h;
                const float v = acc[i][j][r] + bn;
                size_t idx;
                if (z == 2)
                    idx = ((size_t)(bh*128 + (s>>4))*2 + (d>>5))*512
                        + (size_t)((((s>>2)&3)*16 + (d&15))*8 + ((d>>4)&1)*4 + (s&3));
                else
                    idx = ((size_t)(bh*128 + (s>>4))*2 + (d>>5))*512
                        + (size_t)((((d>>3)&3)*16 + (s&15))*8 + (d&7));
                out[idx] = (_Float16)v;
            }
        }
    }
}

// ---------------------------------------------------- pass 1: PV + denominators
// (unchanged from R10 — verified; lane-linear LDS writes/reads, 0 conflicts)
__global__ __launch_bounds__(256) void pv_kernel(
    const _Float16* __restrict__ Qf, const _Float16* __restrict__ Kf,
    const _Float16* __restrict__ Vf, const float* __restrict__ emo_bias,
    const float* __restrict__ modv, _Float16* __restrict__ attended,
    float* __restrict__ Ldenom)
{
    __shared__ _Float16 lK[2][4096];      // 2 x 8 KB
    __shared__ _Float16 lV[2][4096];      // 2 x 8 KB

    const int tid  = threadIdx.x;
    const int lane = tid & 63;
    const int l16  = lane & 15;
    const int g    = lane >> 4;
    const int w    = tid >> 6;
    const int n    = blockIdx.x;
    const int work = (n & 7)*128 + (n >> 3);   // bijective for 1024 blocks
    const int qt   = work & 31;
    const int bh   = work >> 5;
    const int b    = bh >> 3, h = bh & 7;
    const int q0   = qt*64 + w*16;

    const float mod = modv[b];
    const float sm2 = 0.125f * mod * LOG2E;
    const float bm2 = emo_bias[h] * mod * LOG2E;

    const size_t fB = (size_t)bh * 128;

    half8_t qf[2];
    #pragma unroll
    for (int c = 0; c < 2; ++c)
        qf[c] = *(const half8_t*)(Qf + ((fB + (q0>>4))*2 + c)*512 + lane*8);

    {
        const _Float16* gk = Kf + (fB)*1024 + tid*16;
        const _Float16* gv = Vf + (fB)*1024 + tid*16;
        *(half8_t*)(&lK[0][tid*16])     = *(const half8_t*)(gk);
        *(half8_t*)(&lK[0][tid*16 + 8]) = *(const half8_t*)(gk + 8);
        *(half8_t*)(&lV[0][tid*16])     = *(const half8_t*)(gv);
        *(half8_t*)(&lV[0][tid*16 + 8]) = *(const half8_t*)(gv + 8);
    }
    __syncthreads();

    f32x4 acc[4] = {};
    float lsum = 0.f;
    int cur = 0;
    for (int grp = 0; grp < SEQ/64; ++grp){
        half8_t rk0, rk1, rv0, rv1;
        if (grp < SEQ/64 - 1){
            const _Float16* gk = Kf + (fB + (size_t)(grp+1)*4)*1024 + tid*16;
            const _Float16* gv = Vf + (fB + (size_t)(grp+1)*4)*1024 + tid*16;
            rk0 = *(const half8_t*)(gk);
            rk1 = *(const half8_t*)(gk + 8);
            rv0 = *(const half8_t*)(gv);
            rv1 = *(const half8_t*)(gv + 8);
        }
        const _Float16* kb = &lK[cur][0];
        const _Float16* vb = &lV[cur][0];
        #pragma unroll
        for (int t = 0; t < 4; ++t){
            half8_t k0 = *(const half8_t*)(kb + (t*2+0)*512 + lane*8);
            half8_t k1 = *(const half8_t*)(kb + (t*2+1)*512 + lane*8);
            f32x4 s = {};
            s = __builtin_amdgcn_mfma_f32_16x16x32_f16(k0, qf[0], s, 0, 0, 0);
            s = __builtin_amdgcn_mfma_f32_16x16x32_f16(k1, qf[1], s, 0, 0, 0);
            float e0 = EXP2F(s[0]*sm2 + bm2);
            float e1 = EXP2F(s[1]*sm2 + bm2);
            float e2 = EXP2F(s[2]*sm2 + bm2);
            float e3 = EXP2F(s[3]*sm2 + bm2);
            lsum += (e0 + e1) + (e2 + e3);
            half2_t plo = PKRTZ(e0, e1), phi = PKRTZ(e2, e3);
            half4_t pf  = __builtin_shufflevector(plo, phi, 0, 1, 2, 3);
            half8_t vp0 = *(const half8_t*)(vb + (t*2+0)*512 + lane*8);
            half8_t vp1 = *(const half8_t*)(vb + (t*2+1)*512 + lane*8);
            half4_t v0 = __builtin_shufflevector(vp0, vp0, 0, 1, 2, 3);
            half4_t v1 = __builtin_shufflevector(vp0, vp0, 4, 5, 6, 7);
            half4_t v2 = __builtin_shufflevector(vp1, vp1, 0, 1, 2, 3);
            half4_t v3 = __builtin_shufflevector(vp1, vp1, 4, 5, 6, 7);
            acc[0] = __builtin_amdgcn_mfma_f32_16x16x16f16(pf, v0, acc[0], 0, 0, 0);
            acc[1] = __builtin_amdgcn_mfma_f32_16x16x16f16(pf, v1, acc[1], 0, 0, 0);
            acc[2] = __builtin_amdgcn_mfma_f32_16x16x16f16(pf, v2, acc[2], 0, 0, 0);
            acc[3] = __builtin_amdgcn_mfma_f32_16x16x16f16(pf, v3, acc[3], 0, 0, 0);
        }
        if (grp < SEQ/64 - 1){
            _Float16* dk = &lK[cur^1][tid*16];
            _Float16* dv = &lV[cur^1][tid*16];
            *(half8_t*)(dk)     = rk0;
            *(half8_t*)(dk + 8) = rk1;
            *(half8_t*)(dv)     = rv0;
            *(half8_t*)(dv + 8) = rv1;
        }
        __syncthreads();
        cur ^= 1;
    }

    lsum += __shfl_xor(lsum, 16, 64);
    lsum += __shfl_xor(lsum, 32, 64);
    if (g == 0) Ldenom[(size_t)bh*SEQ + q0 + l16] = lsum;
    const float inv = 1.0f / lsum;
    float invr[4];
    #pragma unroll
    for (int r = 0; r < 4; ++r)
        invr[r] = __shfl(inv, 4*g + r, 64);
    #pragma unroll
    for (int c = 0; c < 4; ++c)
        #pragma unroll
        for (int r = 0; r < 4; ++r)
            attended[(size_t)(b*SEQ + q0 + 4*g + r)*EMB + h*64 + 16*c + l16]
                = (_Float16)(acc[c][r] * invr[r]);
}

// ------------------------------------------- pass 2: softmax mean over heads
// (unchanged from R10 — verified)
__global__ __launch_bounds__(256) void mean_kernel(
    const _Float16* __restrict__ Qf, const _Float16* __restrict__ Kf,
    const float* __restrict__ emo_bias, const float* __restrict__ modv,
    const float* __restrict__ Ldenom, float* __restrict__ mean_out)
{
    const int tid  = threadIdx.x;
    const int w    = tid >> 6;
    const int lane = tid & 63;
    const int l16  = lane & 15;
    const int g    = lane >> 4;
    const int n    = blockIdx.x;
    const int work = (n & 7)*512 + (n >> 3);
    const int b    = work >> 10;
    const int ky   = (work >> 7) & 7;
    const int qt   = work & 127;
    const int q0   = qt * 16;
    const int k0w  = ky*256 + w*64;

    const float mod = modv[b];
    const float sm2 = 0.125f * mod * LOG2E;

    f32x4 msum[4] = {};
    for (int hp = 0; hp < HEADS/2; ++hp){
        const int h0 = 2*hp, h1 = 2*hp + 1;
        const size_t lo0 = (size_t)(b*HEADS + h0) * SEQ;
        const size_t lo1 = (size_t)(b*HEADS + h1) * SEQ;
        const size_t f0  = (size_t)(b*HEADS + h0) * 128;
        const size_t f1  = (size_t)(b*HEADS + h1) * 128;
        const float bm20 = emo_bias[h0] * mod * LOG2E;
        const float bm21 = emo_bias[h1] * mod * LOG2E;
        half8_t qa0 = *(const half8_t*)(Qf + ((f0 + (q0>>4))*2 + 0)*512 + lane*8);
        half8_t qa1 = *(const half8_t*)(Qf + ((f0 + (q0>>4))*2 + 1)*512 + lane*8);
        half8_t qb0 = *(const half8_t*)(Qf + ((f1 + (q0>>4))*2 + 0)*512 + lane*8);
        half8_t qb1 = *(const half8_t*)(Qf + ((f1 + (q0>>4))*2 + 1)*512 + lane*8);
        float iA[4], iB[4];
        #pragma unroll
        for (int r = 0; r < 4; ++r){
            iA[r] = 1.0f / Ldenom[lo0 + q0 + 4*g + r];
            iB[r] = 1.0f / Ldenom[lo1 + q0 + 4*g + r];
        }
        #pragma unroll
        for (int j = 0; j < 4; ++j){
            const int kc = (k0w >> 4) + j;
            half8_t ka0 = *(const half8_t*)(Kf + ((f0 + kc)*2 + 0)*512 + lane*8);
            half8_t ka1 = *(const half8_t*)(Kf + ((f0 + kc)*2 + 1)*512 + lane*8);
            half8_t kb0 = *(const half8_t*)(Kf + ((f1 + kc)*2 + 0)*512 + lane*8);
            half8_t kb1 = *(const half8_t*)(Kf + ((f1 + kc)*2 + 1)*512 + lane*8);
            f32x4 sA = {}, sB = {};
            sA = __builtin_amdgcn_mfma_f32_16x16x32_f16(qa0, ka0, sA, 0, 0, 0);
            sA = __builtin_amdgcn_mfma_f32_16x16x32_f16(qa1, ka1, sA, 0, 0, 0);
            sB = __builtin_amdgcn_mfma_f32_16x16x32_f16(qb0, kb0, sB, 0, 0, 0);
            sB = __builtin_amdgcn_mfma_f32_16x16x32_f16(qb1, kb1, sB, 0, 0, 0);
            #pragma unroll
            for (int r = 0; r < 4; ++r){
                float pa = EXP2F(sA[r]*sm2 + bm20) * iA[r];
                float pb = EXP2F(sB[r]*sm2 + bm21) * iB[r];
                msum[j][r] += pa + pb;
            }
        }
    }
    #pragma unroll
    for (int j = 0; j < 4; ++j)
        #pragma unroll
        for (int r = 0; r < 4; ++r)
            mean_out[(size_t)(b*SEQ + q0 + 4*g + r)*SEQ + k0w + j*16 + l16]
                = msum[j][r] * (1.0f/HEADS);
}

// ------------------------------------------------- output projection (LDS GEMM)
// Same XOR-swizzled row-major LDS as qkv.
__global__ __launch_bounds__(256) void outproj_kernel(
    const _Float16* __restrict__ A, const float* __restrict__ W,
    const float* __restrict__ bias, float* __restrict__ out)
{
    __shared__ _Float16 lA[128*64];
    __shared__ _Float16 lB[64*64];

    const int tid  = threadIdx.x;
    const int wid  = tid >> 6;
    const int lane = tid & 63;
    const int l16  = lane & 15;
    const int g    = lane >> 4;
    const int l7   = l16 & 7;
    const int mb = blockIdx.x;
    const int nb = blockIdx.y;
    const int wm = (wid >> 1)*64;
    const int wn = (wid & 1)*32;
    const int tR = tid >> 3;
    const int c8 = tid & 7;

    f32x4 acc[4][2] = {};
    for (int ks = 0; ks < 8; ++ks){
        __syncthreads();
        #pragma unroll
        for (int p = 0; p < 4; ++p){
            const int R = p*32 + tR;
            half8_t h = *(const half8_t*)(A + (size_t)(mb*128 + R)*EMB + ks*64 + c8*8);
            *(half8_t*)(lA + R*64 + ((c8 ^ (R & 7))*8)) = h;
        }
        #pragma unroll
        for (int p = 0; p < 2; ++p){
            const int R = p*32 + tR;
            half8_t h = cvt8(W + (size_t)(nb*64 + R)*EMB + ks*64 + c8*8);
            *(half8_t*)(lB + R*64 + ((c8 ^ (R & 7))*8)) = h;
        }
        __syncthreads();
        #pragma unroll
        for (int u = 0; u < 2; ++u){
            half8_t af[4], bf[2];
            #pragma unroll
            for (int i = 0; i < 4; ++i){
                const int rA = wm + i*16 + l16;
                af[i] = *(half8_t*)(lA + rA*64 + (((u*4 + g) ^ l7)*8));
            }
            #pragma unroll
            for (int j = 0; j < 2; ++j){
                const int rB = wn + j*16 + l16;
                bf[j] = *(half8_t*)(lB + rB*64 + (((u*4 + g) ^ l7)*8));
            }
            #pragma unroll
            for (int i = 0; i < 4; ++i)
                #pragma unroll
                for (int j = 0; j < 2; ++j)
                    acc[i][j] = __builtin_amdgcn_mfma_f32_16x16x32_f16(af[i], bf[j], acc[i][j], 0, 0, 0);
        }
    }
    #pragma unroll
    for (int j = 0; j < 2; ++j){
        const int nn = nb*64 + wn + j*16 + l16;
        const float bn = bias[nn];
        #pragma unroll
        for (int i = 0; i < 4; ++i)
            #pragma unroll
            for (int r = 0; r < 4; ++r){
                const int m = mb*128 + wm + i*16 + 4*g + r;
                out[(size_t)m*EMB + nn] = acc[i][j][r] + bn;
            }
    }
}

// ---------------------------------------------------------------------- host
extern "C" void kernel_launch(void* const* d_in, const int* in_sizes, int n_in,
                              void* d_out, int out_size, void* d_ws, size_t ws_size,
                              hipStream_t stream)
{
    const float* query = (const float*)d_in[0];
    const float* key_  = (const float*)d_in[1];
    const float* value = (const float*)d_in[2];
    const float* emo   = (const float*)d_in[3];
    const float* Wq = (const float*)d_in[4];
    const float* bq = (const float*)d_in[5];
    const float* Wk = (const float*)d_in[6];
    const float* bk = (const float*)d_in[7];
    const float* Wv = (const float*)d_in[8];
    const float* bv = (const float*)d_in[9];
    const float* Wo = (const float*)d_in[10];
    const float* bo = (const float*)d_in[11];
    const float* emo_bias = (const float*)d_in[12];

    const size_t NTOK = (size_t)BATCH * SEQ * EMB;   // 4,194,304
    _Float16* ws       = (_Float16*)d_ws;
    _Float16* Qp       = ws;                          // ws usage: exactly 32 MiB
    _Float16* Kp       = ws + NTOK;
    _Float16* Vt       = ws + 2*NTOK;
    _Float16* attended = ws + 3*NTOK;

    float* out0     = (float*)d_out;
    float* mean_out = out0 + NTOK;
    float* Ldenom   = out0;                           // scratch in out0 region
    float* modv     = out0 + (size_t)BATCH*HEADS*SEQ; // overwritten by outproj

    mod_kernel<<<1, 64, 0, stream>>>(emo, modv);
    qkv_kernel<<<dim3(64, 8, 3), 256, 0, stream>>>(query, key_, value, Wq, Wk, Wv,
                                                   bq, bk, bv, Qp, Kp, Vt);
    pv_kernel<<<BATCH*HEADS*(SEQ/64), 256, 0, stream>>>(Qp, Kp, Vt, emo_bias, modv, attended, Ldenom);
    mean_kernel<<<BATCH*(SEQ/16)*(SEQ/256), 256, 0, stream>>>(Qp, Kp, emo_bias, modv, Ldenom, mean_out);
    outproj_kernel<<<dim3(64, 8), 256, 0, stream>>>(attended, Wo, bo, out0);
}